// Round 5
// baseline (431.624 us; speedup 1.0000x reference)
//
#include <hip/hip_runtime.h>
#include <math.h>

// ---- weight buffer layout ----
// fp32 section (dwords 0..1232):
// W1[16][5]@0 b1@80 | W2[32][16]@96 b2@608 | W3[16][35]@640 b3@1200 | W4[16]@1216 b4@1232
// packed fp16 section (uint view at dword offset 1280):
// w1a[16]@0 | w1b[16]@16 | w1c[16]@32 | w2pk[32][8]@48 | b1f[16]@304 | b2f[32]@320
#define WTOT  1233
#define PKOFS 1280
#define PKTOT 352

typedef __fp16 h2 __attribute__((ext_vector_type(2)));
typedef __fp16 f16x8 __attribute__((ext_vector_type(8)));
typedef float f32x16 __attribute__((ext_vector_type(16)));

// 12-byte edge record (src, dst, packed ea)
struct ERec { int s; int d; unsigned int ea; };

__device__ __forceinline__ h2 u2h(unsigned int u) { return __builtin_bit_cast(h2, u); }
__device__ __forceinline__ unsigned int h2u(h2 h) { return __builtin_bit_cast(unsigned int, h); }
#define DOT2(a, b, c) __builtin_amdgcn_fdot2((a), (b), (c), false)

__device__ __forceinline__ float softplus_f(float x) {
  return fmaxf(x, 0.f) + log1pf(expf(-fabsf(x)));
}

struct PrepArgs {
  const float* wmu[4]; const float* wrho[4]; const float* epsw[4];
  const float* bmu[4]; const float* brho[4]; const float* epsb[4];
  float* out; int* bucketCur; int nbuck;
};

// single block 1024: sample all weights, pack fp16 section, zero bucketCur
__global__ void prep_all_kernel(PrepArgs a) {
  const int wsz[4] = {80, 512, 560, 16};
  const int wof[4] = {0, 96, 640, 1216};
  const int bsz[4] = {16, 32, 16, 1};
  const int bof[4] = {80, 608, 1200, 1232};
  float* wg = a.out;
  int tid = threadIdx.x;
  if (tid < a.nbuck) a.bucketCur[tid] = 0;
#pragma unroll
  for (int l = 0; l < 4; l++) {
    for (int i = tid; i < wsz[l]; i += 1024)
      wg[wof[l] + i] = a.wmu[l][i] + softplus_f(a.wrho[l][i]) * a.epsw[l][i];
    for (int i = tid; i < bsz[l]; i += 1024)
      wg[bof[l] + i] = a.bmu[l][i] + softplus_f(a.brho[l][i]) * a.epsb[l][i];
  }
  __syncthreads();
  unsigned int* wp = (unsigned int*)(wg + PKOFS);
  int t = tid;
  if (t < 16) {
    wp[t]      = h2u(h2{(__fp16)wg[t * 5 + 0], (__fp16)wg[t * 5 + 1]});
    wp[16 + t] = h2u(h2{(__fp16)wg[t * 5 + 2], (__fp16)0.f});
    wp[32 + t] = h2u(h2{(__fp16)wg[t * 5 + 3], (__fp16)wg[t * 5 + 4]});
    ((float*)wp)[304 + t] = wg[80 + t];
  }
  if (t < 32) {
    ((float*)wp)[320 + t] = wg[608 + t];
    for (int j = 0; j < 8; j++)
      wp[48 + t * 8 + j] =
          h2u(h2{(__fp16)wg[96 + t * 16 + 2 * j], (__fp16)wg[96 + t * 16 + 2 * j + 1]});
  }
}

// per-block LDS histogram of dst buckets (bucket = dst>>8), flush to bucketCur
__global__ __launch_bounds__(1024) void bhist_kernel(const int* __restrict__ dst,
                                                     int* __restrict__ bucketCur,
                                                     int E, int NBUCK) {
  __shared__ int h[1024];
  int tid = threadIdx.x;
  for (int i = tid; i < NBUCK; i += 1024) h[i] = 0;
  __syncthreads();
  int base = blockIdx.x * 8192;
#pragma unroll
  for (int r = 0; r < 8; r++) {
    int e = base + r * 1024 + tid;
    if (e < E) atomicAdd(&h[dst[e] >> 8], 1);
  }
  __syncthreads();
  for (int i = tid; i < NBUCK; i += 1024) {
    int c = h[i];
    if (c) atomicAdd(&bucketCur[i], c);
  }
}

// single-block exclusive scan over NBUCK (<=1024) counts held in bucketCur;
// writes bucketOff[0..NBUCK] and re-seeds bucketCur with the exclusive offsets
__global__ __launch_bounds__(1024) void scanBk_kernel(int* __restrict__ bucketCur,
                                                      int* __restrict__ bucketOff,
                                                      int NBUCK) {
  __shared__ int wsum[16];
  __shared__ int woff[16];
  int tid = threadIdx.x, lane = tid & 63, wid = tid >> 6;
  int v = (tid < NBUCK) ? bucketCur[tid] : 0;
  int x = v;
#pragma unroll
  for (int off = 1; off < 64; off <<= 1) {
    int t = __shfl_up(x, off, 64);
    if (lane >= off) x += t;
  }
  if (lane == 63) wsum[wid] = x;
  __syncthreads();
  if (wid == 0) {
    int s = (lane < 16) ? wsum[lane] : 0;
#pragma unroll
    for (int off = 1; off < 16; off <<= 1) {
      int t = __shfl_up(s, off, 64);
      if (lane >= off) s += t;
    }
    if (lane < 16) woff[lane] = s - wsum[lane];
  }
  __syncthreads();
  int excl = woff[wid] + x - v;
  if (tid < NBUCK) {
    bucketOff[tid] = excl;
    bucketCur[tid] = excl;
    if (tid == NBUCK - 1) bucketOff[NBUCK] = excl + v;
  }
}

// partition edges into bucket regions: per-block LDS hist -> global reserve ->
// LDS-cursor append. AoS ERec (12B/edge), 8192 edges/block (R3 lesson:
// occupancy >> chunk depth). 256-node buckets (dst>>8) make per-bucket chunks
// ~21 records (~252B) to cut write-allocate amplification vs 128-node buckets.
__global__ __launch_bounds__(1024) void part_kernel(
    const int* __restrict__ src, const int* __restrict__ dst,
    const float2* __restrict__ ea, int* __restrict__ bucketCur,
    ERec* __restrict__ brec, int E, int NBUCK) {
  __shared__ int h[1024];
  int tid = threadIdx.x;
  for (int i = tid; i < NBUCK; i += 1024) h[i] = 0;
  __syncthreads();
  int base = blockIdx.x * 8192;
  int d[8], s[8];
  unsigned int a[8];
  bool v[8];
#pragma unroll
  for (int j = 0; j < 8; j++) {
    int e = base + j * 1024 + tid;
    v[j] = e < E;
    if (v[j]) {
      d[j] = dst[e];
      s[j] = src[e];
      float2 t = ea[e];
      a[j] = h2u(__builtin_amdgcn_cvt_pkrtz(t.x, t.y));
      atomicAdd(&h[d[j] >> 8], 1);
    }
  }
  __syncthreads();
  for (int i = tid; i < NBUCK; i += 1024) {
    int c = h[i];
    h[i] = c ? atomicAdd(&bucketCur[i], c) : 0;
  }
  __syncthreads();
#pragma unroll
  for (int j = 0; j < 8; j++) {
    if (v[j]) {
      int pos = atomicAdd(&h[d[j] >> 8], 1);
      ERec t; t.s = s[j]; t.d = d[j]; t.ea = a[j];
      brec[pos] = t;
    }
  }
}

// per-bucket degree via LDS histogram (256 nodes/bucket, 512 threads)
__global__ __launch_bounds__(512) void deg_kernel(const ERec* __restrict__ brec,
                                                  const int* __restrict__ bucketOff,
                                                  int* __restrict__ deg, int N) {
  __shared__ int cnt[256];
  int b = blockIdx.x, tid = threadIdx.x;
  if (tid < 256) cnt[tid] = 0;
  __syncthreads();
  int e0 = bucketOff[b], e1 = bucketOff[b + 1];
  for (int i = e0 + tid; i < e1; i += 512) atomicAdd(&cnt[brec[i].d & 255], 1);
  __syncthreads();
  int node = b * 256 + tid;
  if (tid < 256 && node < N) deg[node] = cnt[tid];
}

// ---- 3-phase exclusive scan over PADDED deg ((deg+3)&~3) -> cursor ----
__global__ void scanA_kernel(const int* __restrict__ deg, int* __restrict__ part, int n) {
  __shared__ int ws[16];
  int tid = threadIdx.x;
  int i = blockIdx.x * 1024 + tid;
  int v = 0;
  if (i < n) v = (deg[i] + 3) & ~3;
#pragma unroll
  for (int off = 32; off >= 1; off >>= 1) v += __shfl_down(v, off, 64);
  if ((tid & 63) == 0) ws[tid >> 6] = v;
  __syncthreads();
  if (tid == 0) {
    int s = 0;
#pragma unroll
    for (int k = 0; k < 16; k++) s += ws[k];
    part[blockIdx.x] = s;
  }
}

__global__ void scanB_kernel(int* __restrict__ part, int P, int* __restrict__ etot) {
  int lane = threadIdx.x;
  int carry = 0;
  for (int base = 0; base < P; base += 64) {
    int i = base + lane;
    int v = (i < P) ? part[i] : 0;
    int x = v;
#pragma unroll
    for (int off = 1; off < 64; off <<= 1) {
      int t = __shfl_up(x, off, 64);
      if (lane >= off) x += t;
    }
    if (i < P) part[i] = carry + x - v;
    carry += __shfl(x, 63, 64);
  }
  if (lane == 0) *etot = carry;  // total padded edge count
}

__global__ void scanC_kernel(const int* __restrict__ deg, const int* __restrict__ part,
                             int* __restrict__ cursor, int n) {
  __shared__ int wsum[16];
  __shared__ int woff[16];
  int tid = threadIdx.x, lane = tid & 63, wid = tid >> 6;
  int i = blockIdx.x * 1024 + tid;
  int v = 0;
  if (i < n) v = (deg[i] + 3) & ~3;
  int x = v;
#pragma unroll
  for (int off = 1; off < 64; off <<= 1) {
    int t = __shfl_up(x, off, 64);
    if (lane >= off) x += t;
  }
  if (lane == 63) wsum[wid] = x;
  __syncthreads();
  if (wid == 0) {
    int s = (lane < 16) ? wsum[lane] : 0;
#pragma unroll
    for (int off = 1; off < 16; off <<= 1) {
      int t = __shfl_up(s, off, 64);
      if (lane >= off) s += t;
    }
    if (lane < 16) woff[lane] = s - wsum[lane];
  }
  __syncthreads();
  if (i < n) cursor[i] = part[blockIdx.x] + woff[wid] + x - v;
}

// per-bucket final scatter into padded per-node regions; pad slots filled with
// a DUPLICATE real edge (max idempotent) so all dst-runs are 4-aligned.
// 256-node buckets, 512 threads.
__global__ __launch_bounds__(512) void scat_kernel(
    const ERec* __restrict__ brec, const int* __restrict__ bucketOff,
    const int* __restrict__ cursor, ERec* __restrict__ erec, int N) {
  __shared__ int lcur[256];
  int b = blockIdx.x, tid = threadIdx.x;
  int node = b * 256 + tid;
  if (tid < 256) lcur[tid] = (node < N) ? cursor[node] : 0;
  __syncthreads();
  int e0 = bucketOff[b], e1 = bucketOff[b + 1];
  for (int i = e0 + tid; i < e1; i += 512) {
    ERec t = brec[i];
    int pos = atomicAdd(&lcur[t.d & 255], 1);
    erec[pos] = t;
  }
  __syncthreads();
  if (tid < 256 && node < N) {
    int cur = cursor[node];
    int endR = lcur[tid];                       // cur + real deg
    int endP = cur + ((endR - cur + 3) & ~3);   // cur + padded deg
    if (endR > cur) {
      ERec rep = erec[cur];
      for (int k = endR; k < endP; k++) erec[k] = rep;
    }
  }
}

// pack x to fp16 pairs + zero agg32 rows (N+1 rows x 32 dwords)
__global__ void xpack_kernel(const float* __restrict__ x, uint2* __restrict__ xpk,
                             unsigned int* __restrict__ agg32, int n) {
  int i = blockIdx.x * blockDim.x + threadIdx.x;
  if (i < n) {
    h2 a = __builtin_amdgcn_cvt_pkrtz(x[3 * i], x[3 * i + 1]);
    h2 b = __builtin_amdgcn_cvt_pkrtz(x[3 * i + 2], 0.f);
    xpk[i] = make_uint2(h2u(a), h2u(b));
    uint4 z = make_uint4(0u, 0u, 0u, 0u);
    uint4* ap = (uint4*)(agg32 + (size_t)i * 32);
#pragma unroll
    for (int k = 0; k < 8; k++) ap[k] = z;
    if (i == 0) {
      uint4* as = (uint4*)(agg32 + (size_t)n * 32);
#pragma unroll
      for (int k = 0; k < 8; k++) as[k] = z;
    }
  }
}

// edge kernel (R13): 2 edges/lane, 128-edge window per wave. Layer1 5->16 fp16
// dot2 twice (independent dep chains hide erec/xpk gather latency); m1 rows
// staged to wave-private LDS (stride 12 dwords); layer2 16->32 via FOUR
// mfma_f32_32x32x16_f16. D layout: col=lane&31 (feature),
// row = (reg&3)+8*(reg>>2)+4*(lane>>5) => 4-edge block index 8g+2q+h.
// Runs 4-aligned (padded scatter); per run: 16 predicated maxes + one
// shfl_xor(32) + f32-as-u32 atomicMax (order-free => window-crossing runs need
// no special casing). No block barrier (wave-private LDS + lgkmcnt fence).
__global__ __launch_bounds__(256) void edge_kernel(
    const uint2* __restrict__ xpk, const ERec* __restrict__ erec,
    unsigned int* __restrict__ agg32,
    const float* __restrict__ wg, const int* __restrict__ pEtot, int N) {
  __shared__ __align__(16) unsigned int lds[4][128][12];  // 24KB
  const unsigned int* wp = (const unsigned int*)(wg + PKOFS);
  const float* bf = (const float*)wp;
  const int Etot = *pEtot;
  const int tid = threadIdx.x;
  const int lane = tid & 63;
  const int wslot = tid >> 6;
  const int wbase = blockIdx.x * 512 + wslot * 128;
  if (wbase >= Etot) return;   // whole-wave tail skip (no block barrier below)

  int e0 = wbase + lane, e1 = wbase + 64 + lane;
  ERec r0, r1;
  r0.s = 0; r0.d = N; r0.ea = 0u;
  r1 = r0;
  if (e0 < Etot) r0 = erec[e0];
  if (e1 < Etot) r1 = erec[e1];
  uint2 xs0 = xpk[r0.s];
  uint2 xs1 = xpk[r1.s];

  // ---- layer1 for both edges: 5->16 fp16 dot2, relu, pack ----
  h2 p01a = u2h(xs0.x), p2va = u2h(xs0.y), peaa = u2h(r0.ea);
  h2 p01b = u2h(xs1.x), p2vb = u2h(xs1.y), peab = u2h(r1.ea);
  unsigned int m1a[8], m1b[8];
#pragma unroll
  for (int p = 0; p < 8; p++) {
    const int oA = 2 * p, oB = 2 * p + 1;
    h2 wA0 = u2h(wp[oA]), wA1 = u2h(wp[16 + oA]), wA2 = u2h(wp[32 + oA]);
    h2 wB0 = u2h(wp[oB]), wB1 = u2h(wp[16 + oB]), wB2 = u2h(wp[32 + oB]);
    float bA = bf[304 + oA], bB = bf[304 + oB];
    float sAa = DOT2(p01a, wA0, DOT2(p2va, wA1, DOT2(peaa, wA2, bA)));
    float sBa = DOT2(p01a, wB0, DOT2(p2va, wB1, DOT2(peaa, wB2, bB)));
    float sAb = DOT2(p01b, wA0, DOT2(p2vb, wA1, DOT2(peab, wA2, bA)));
    float sBb = DOT2(p01b, wB0, DOT2(p2vb, wB1, DOT2(peab, wB2, bB)));
    m1a[p] = h2u(__builtin_amdgcn_cvt_pkrtz(fmaxf(sAa, 0.f), fmaxf(sBa, 0.f)));
    m1b[p] = h2u(__builtin_amdgcn_cvt_pkrtz(fmaxf(sAb, 0.f), fmaxf(sBb, 0.f)));
  }

  // ---- stage m1 rows (lane and 64+lane) into wave-private LDS ----
  uint4* rp0 = (uint4*)&lds[wslot][lane][0];
  rp0[0] = make_uint4(m1a[0], m1a[1], m1a[2], m1a[3]);
  rp0[1] = make_uint4(m1a[4], m1a[5], m1a[6], m1a[7]);
  uint4* rp1 = (uint4*)&lds[wslot][64 + lane][0];
  rp1[0] = make_uint4(m1b[0], m1b[1], m1b[2], m1b[3]);
  rp1[1] = make_uint4(m1b[4], m1b[5], m1b[6], m1b[7]);
  asm volatile("s_waitcnt lgkmcnt(0)" ::: "memory");
  __builtin_amdgcn_sched_barrier(0);

  const int col = lane & 31;   // output feature (D col)
  const int h = lane >> 5;     // k-half / row-half selector
  f16x8 bfrag = __builtin_bit_cast(f16x8, *(const uint4*)&wp[48 + col * 8 + 4 * h]);
  float bias = bf[320 + col];
  f32x16 cini;
#pragma unroll
  for (int i = 0; i < 16; i++) cini[i] = bias;

  // ---- 4 MFMAs (32 edges each) + per-4-edge-block max (relu folded) ----
  float bm[4][4];
#pragma unroll
  for (int g = 0; g < 4; g++) {
    f16x8 a = __builtin_bit_cast(f16x8, *(const uint4*)&lds[wslot][32 * g + col][4 * h]);
    f32x16 acc = __builtin_amdgcn_mfma_f32_32x32x16_f16(a, bfrag, cini, 0, 0, 0);
#pragma unroll
    for (int q = 0; q < 4; q++)
      bm[g][q] = fmaxf(fmaxf(acc[4 * q], acc[4 * q + 1]),
                       fmaxf(acc[4 * q + 2], fmaxf(acc[4 * q + 3], 0.f)));
  }

  // ---- run structure over 128 positions (heads 4-aligned by construction) ----
  int d0 = r0.d, d1 = r1.d;
  int d0p4 = __shfl_up(d0, 4, 64);
  int d1p4 = __shfl_up(d1, 4, 64);
  int d0t = __shfl(d0, 60, 64);   // predecessor of position 64
  bool head0 = ((lane & 3) == 0) && (lane == 0 || d0 != d0p4);
  bool head1 = ((lane & 3) == 0) && (lane == 0 ? (d1 != d0t) : (d1 != d1p4));
  unsigned long long m0 = __ballot(head0);
  unsigned long long m1 = __ballot(head1);

  while (m0 | m1) {
    int a;
    if (m0) { a = (int)__builtin_ctzll(m0); m0 &= m0 - 1; }
    else    { a = 64 + (int)__builtin_ctzll(m1); m1 &= m1 - 1; }
    int b = m0 ? (int)__builtin_ctzll(m0)
               : (m1 ? 64 + (int)__builtin_ctzll(m1) : 128);
    int rd = (a < 64) ? __shfl(d0, a, 64) : __shfl(d1, a - 64, 64);
    int A = a >> 2, B = b >> 2;   // 4-edge block range of this run (0..32)
    float mx = 0.f;
#pragma unroll
    for (int g = 0; g < 4; g++) {
#pragma unroll
      for (int q = 0; q < 4; q++) {
        int blk = 8 * g + 2 * q + h;
        bool in = (blk >= A) && (blk < B);
        mx = fmaxf(mx, in ? bm[g][q] : 0.f);
      }
    }
    mx = fmaxf(mx, __shfl_xor(mx, 32, 64));
    if (lane < 32 && rd < N)
      atomicMax(agg32 + (size_t)rd * 32 + col, __float_as_uint(mx));
  }
}

// node-parallel: read agg row (f32 bits), zero it for next iteration, node MLP.
__global__ __launch_bounds__(256) void node_kernel(
    const float* __restrict__ x, const float* __restrict__ cin,
    float* __restrict__ cout, uint2* __restrict__ xpk,
    float* __restrict__ outFinal, unsigned int* __restrict__ agg32,
    const float* __restrict__ wg, int n) {
  int nid = blockIdx.x * blockDim.x + threadIdx.x;
  if (nid >= n) return;
  uint4* ap = (uint4*)(agg32 + (size_t)nid * 32);
  uint4 q[8];
#pragma unroll
  for (int i = 0; i < 8; i++) q[i] = ap[i];
  uint4 z = make_uint4(0u, 0u, 0u, 0u);
#pragma unroll
  for (int i = 0; i < 8; i++) ap[i] = z;
  float av[32];
#pragma unroll
  for (int i = 0; i < 8; i++) {
    av[4 * i + 0] = __uint_as_float(q[i].x);
    av[4 * i + 1] = __uint_as_float(q[i].y);
    av[4 * i + 2] = __uint_as_float(q[i].z);
    av[4 * i + 3] = __uint_as_float(q[i].w);
  }
  float x0 = x[3 * nid], x1 = x[3 * nid + 1];
  float x2 = cin ? cin[nid] : x[3 * nid + 2];
  float h[16];
#pragma unroll
  for (int o = 0; o < 16; o++) {
    float sa = wg[1200 + o];
    sa = fmaf(wg[640 + o * 35 + 0], x0, sa);
    sa = fmaf(wg[640 + o * 35 + 1], x1, sa);
    sa = fmaf(wg[640 + o * 35 + 2], x2, sa);
#pragma unroll
    for (int k = 0; k < 32; k++) sa = fmaf(wg[640 + o * 35 + 3 + k], av[k], sa);
    h[o] = fmaxf(sa, 0.f);
  }
  float z4 = wg[1232];
#pragma unroll
  for (int k = 0; k < 16; k++) z4 = fmaf(wg[1216 + k], h[k], z4);
  float comb = 1.f / (1.f + expf(-z4));
  cout[nid] = comb;
  ((unsigned int*)xpk)[2 * nid + 1] = h2u(__builtin_amdgcn_cvt_pkrtz(comb, 0.f));
  if (outFinal) {
    outFinal[3 * nid] = x0;
    outFinal[3 * nid + 1] = x1;
    outFinal[3 * nid + 2] = comb;
  }
}

extern "C" void kernel_launch(void* const* d_in, const int* in_sizes, int n_in,
                              void* d_out, int out_size, void* d_ws, size_t ws_size,
                              hipStream_t stream) {
  const float* x = (const float*)d_in[0];
  const float* ea = (const float*)d_in[1];
  const int* eidx = (const int*)d_in[2];
  const int N = in_sizes[0] / 3;
  const int E = in_sizes[1] / 2;
  const int* src = eidx;
  const int* dst = eidx + E;
  const int P = (N + 1023) / 1024;
  const int NBUCK = (N + 255) >> 8;  // dst buckets, 256 nodes each (<=1024 for N<=262144)
  const int EP = E + 3 * N;          // padded-edge upper bound (actual in *etot)

  // ---- workspace carve-up ----
  char* p = (char*)d_ws;
  size_t off = 0;
  auto alloc = [&](size_t bytes) -> char* {
    char* r = p + off;
    off = (off + bytes + 255) & ~(size_t)255;
    return r;
  };
  float* wbuf = (float*)alloc((size_t)(PKOFS + PKTOT) * 4);
  int* deg = (int*)alloc((size_t)N * 4);
  int* part = (int*)alloc((size_t)P * 4);
  int* cursor = (int*)alloc((size_t)N * 4);
  int* bucketOff = (int*)alloc(((size_t)NBUCK + 1) * 4);
  int* bucketCur = (int*)alloc((size_t)NBUCK * 4);
  int* etot = (int*)alloc(4);
  ERec* erec = (ERec*)alloc((size_t)EP * sizeof(ERec));  // 12B/edge
  // UNION region: build-phase AoS brec (12B/edge) aliased with run-phase
  // arrays (agg32 (N+1)*128B ~12.9MB, xpk, bufA/B) — all << E*12B
  char* uni = alloc((size_t)E * 12);
  ERec* brec = (ERec*)uni;
  size_t uoff = 0;
  auto ualloc = [&](size_t bytes) -> char* {
    char* r = uni + uoff;
    uoff = (uoff + bytes + 255) & ~(size_t)255;
    return r;
  };
  unsigned int* agg32 = (unsigned int*)ualloc(((size_t)N + 1) * 32 * 4);
  uint2* xpk = (uint2*)ualloc((size_t)N * 8);
  float* bufA = (float*)ualloc((size_t)N * 4);
  float* bufB = (float*)ualloc((size_t)N * 4);
  (void)ws_size;

  PrepArgs pa;
  for (int l = 0; l < 4; l++) {
    pa.wmu[l] = (const float*)d_in[3 + 6 * l + 0];
    pa.wrho[l] = (const float*)d_in[3 + 6 * l + 1];
    pa.bmu[l] = (const float*)d_in[3 + 6 * l + 2];
    pa.brho[l] = (const float*)d_in[3 + 6 * l + 3];
    pa.epsw[l] = (const float*)d_in[3 + 6 * l + 4];
    pa.epsb[l] = (const float*)d_in[3 + 6 * l + 5];
  }
  pa.out = wbuf;
  pa.bucketCur = bucketCur;
  pa.nbuck = NBUCK;

  const int TB = 256;
  auto blocks = [&](int n) { return dim3((n + TB - 1) / TB); };

  prep_all_kernel<<<dim3(1), dim3(1024), 0, stream>>>(pa);
  bhist_kernel<<<dim3((E + 8191) / 8192), dim3(1024), 0, stream>>>(dst, bucketCur, E, NBUCK);
  scanBk_kernel<<<dim3(1), dim3(1024), 0, stream>>>(bucketCur, bucketOff, NBUCK);
  part_kernel<<<dim3((E + 8191) / 8192), dim3(1024), 0, stream>>>(
      src, dst, (const float2*)ea, bucketCur, brec, E, NBUCK);
  deg_kernel<<<dim3(NBUCK), dim3(512), 0, stream>>>(brec, bucketOff, deg, N);
  scanA_kernel<<<dim3(P), dim3(1024), 0, stream>>>(deg, part, N);
  scanB_kernel<<<dim3(1), dim3(64), 0, stream>>>(part, P, etot);
  scanC_kernel<<<dim3(P), dim3(1024), 0, stream>>>(deg, part, cursor, N);
  scat_kernel<<<dim3(NBUCK), dim3(512), 0, stream>>>(brec, bucketOff, cursor, erec, N);
  xpack_kernel<<<blocks(N), dim3(TB), 0, stream>>>(x, xpk, agg32, N);

  float* outp = (float*)d_out;
  const int ebp = (EP + 511) / 512;
  // iter 1
  edge_kernel<<<dim3(ebp), dim3(TB), 0, stream>>>(xpk, erec, agg32, wbuf, etot, N);
  node_kernel<<<blocks(N), dim3(TB), 0, stream>>>(x, nullptr, bufA, xpk, nullptr,
                                                  agg32, wbuf, N);
  // iter 2
  edge_kernel<<<dim3(ebp), dim3(TB), 0, stream>>>(xpk, erec, agg32, wbuf, etot, N);
  node_kernel<<<blocks(N), dim3(TB), 0, stream>>>(x, bufA, bufB, xpk, nullptr,
                                                  agg32, wbuf, N);
  // iter 3
  edge_kernel<<<dim3(ebp), dim3(TB), 0, stream>>>(xpk, erec, agg32, wbuf, etot, N);
  node_kernel<<<blocks(N), dim3(TB), 0, stream>>>(x, bufB, bufA, xpk, outp,
                                                  agg32, wbuf, N);
}

// Round 6
// 364.648 us; speedup vs baseline: 1.1837x; 1.1837x over previous
//
#include <hip/hip_runtime.h>
#include <math.h>

// ---- weight buffer layout ----
// fp32 section (dwords 0..1232):
// W1[16][5]@0 b1@80 | W2[32][16]@96 b2@608 | W3[16][35]@640 b3@1200 | W4[16]@1216 b4@1232
// packed fp16 section (uint view at dword offset 1280):
// w1a[16]@0 | w1b[16]@16 | w1c[16]@32 | w2pk[32][8]@48 | b1f[16]@304 | b2f[32]@320
#define WTOT  1233
#define PKOFS 1280
#define PKTOT 352

typedef __fp16 h2 __attribute__((ext_vector_type(2)));
typedef __fp16 f16x8 __attribute__((ext_vector_type(8)));
typedef float f32x16 __attribute__((ext_vector_type(16)));

// 12-byte edge record (src, dst, packed ea)
struct ERec { int s; int d; unsigned int ea; };

__device__ __forceinline__ h2 u2h(unsigned int u) { return __builtin_bit_cast(h2, u); }
__device__ __forceinline__ unsigned int h2u(h2 h) { return __builtin_bit_cast(unsigned int, h); }
#define DOT2(a, b, c) __builtin_amdgcn_fdot2((a), (b), (c), false)

__device__ __forceinline__ float softplus_f(float x) {
  return fmaxf(x, 0.f) + log1pf(expf(-fabsf(x)));
}

struct PrepArgs {
  const float* wmu[4]; const float* wrho[4]; const float* epsw[4];
  const float* bmu[4]; const float* brho[4]; const float* epsb[4];
  float* out; int* bucketCur; int nbuck;
};

// single block 1024: sample all weights, pack fp16 section, zero bucketCur
__global__ void prep_all_kernel(PrepArgs a) {
  const int wsz[4] = {80, 512, 560, 16};
  const int wof[4] = {0, 96, 640, 1216};
  const int bsz[4] = {16, 32, 16, 1};
  const int bof[4] = {80, 608, 1200, 1232};
  float* wg = a.out;
  int tid = threadIdx.x;
  if (tid < a.nbuck) a.bucketCur[tid] = 0;
#pragma unroll
  for (int l = 0; l < 4; l++) {
    for (int i = tid; i < wsz[l]; i += 1024)
      wg[wof[l] + i] = a.wmu[l][i] + softplus_f(a.wrho[l][i]) * a.epsw[l][i];
    for (int i = tid; i < bsz[l]; i += 1024)
      wg[bof[l] + i] = a.bmu[l][i] + softplus_f(a.brho[l][i]) * a.epsb[l][i];
  }
  __syncthreads();
  unsigned int* wp = (unsigned int*)(wg + PKOFS);
  int t = tid;
  if (t < 16) {
    wp[t]      = h2u(h2{(__fp16)wg[t * 5 + 0], (__fp16)wg[t * 5 + 1]});
    wp[16 + t] = h2u(h2{(__fp16)wg[t * 5 + 2], (__fp16)0.f});
    wp[32 + t] = h2u(h2{(__fp16)wg[t * 5 + 3], (__fp16)wg[t * 5 + 4]});
    ((float*)wp)[304 + t] = wg[80 + t];
  }
  if (t < 32) {
    ((float*)wp)[320 + t] = wg[608 + t];
    for (int j = 0; j < 8; j++)
      wp[48 + t * 8 + j] =
          h2u(h2{(__fp16)wg[96 + t * 16 + 2 * j], (__fp16)wg[96 + t * 16 + 2 * j + 1]});
  }
}

// per-block LDS histogram of dst buckets (bucket = dst>>8), flush to bucketCur
__global__ __launch_bounds__(1024) void bhist_kernel(const int* __restrict__ dst,
                                                     int* __restrict__ bucketCur,
                                                     int E, int NBUCK) {
  __shared__ int h[1024];
  int tid = threadIdx.x;
  for (int i = tid; i < NBUCK; i += 1024) h[i] = 0;
  __syncthreads();
  int base = blockIdx.x * 8192;
#pragma unroll
  for (int r = 0; r < 8; r++) {
    int e = base + r * 1024 + tid;
    if (e < E) atomicAdd(&h[dst[e] >> 8], 1);
  }
  __syncthreads();
  for (int i = tid; i < NBUCK; i += 1024) {
    int c = h[i];
    if (c) atomicAdd(&bucketCur[i], c);
  }
}

// single-block exclusive scan over NBUCK (<=1024) counts held in bucketCur;
// writes bucketOff[0..NBUCK] and re-seeds bucketCur with the exclusive offsets
__global__ __launch_bounds__(1024) void scanBk_kernel(int* __restrict__ bucketCur,
                                                      int* __restrict__ bucketOff,
                                                      int NBUCK) {
  __shared__ int wsum[16];
  __shared__ int woff[16];
  int tid = threadIdx.x, lane = tid & 63, wid = tid >> 6;
  int v = (tid < NBUCK) ? bucketCur[tid] : 0;
  int x = v;
#pragma unroll
  for (int off = 1; off < 64; off <<= 1) {
    int t = __shfl_up(x, off, 64);
    if (lane >= off) x += t;
  }
  if (lane == 63) wsum[wid] = x;
  __syncthreads();
  if (wid == 0) {
    int s = (lane < 16) ? wsum[lane] : 0;
#pragma unroll
    for (int off = 1; off < 16; off <<= 1) {
      int t = __shfl_up(s, off, 64);
      if (lane >= off) s += t;
    }
    if (lane < 16) woff[lane] = s - wsum[lane];
  }
  __syncthreads();
  int excl = woff[wid] + x - v;
  if (tid < NBUCK) {
    bucketOff[tid] = excl;
    bucketCur[tid] = excl;
    if (tid == NBUCK - 1) bucketOff[NBUCK] = excl + v;
  }
}

// partition edges into bucket regions: per-block LDS hist -> global reserve ->
// LDS-cursor append. AoS ERec (12B/edge), 8192 edges/block (R3 lesson:
// occupancy >> chunk depth). 256-node buckets (dst>>8): ~21-record chunks
// (~252B) cut write-allocate amplification (R4->R5 verified win).
__global__ __launch_bounds__(1024) void part_kernel(
    const int* __restrict__ src, const int* __restrict__ dst,
    const float2* __restrict__ ea, int* __restrict__ bucketCur,
    ERec* __restrict__ brec, int E, int NBUCK) {
  __shared__ int h[1024];
  int tid = threadIdx.x;
  for (int i = tid; i < NBUCK; i += 1024) h[i] = 0;
  __syncthreads();
  int base = blockIdx.x * 8192;
  int d[8], s[8];
  unsigned int a[8];
  bool v[8];
#pragma unroll
  for (int j = 0; j < 8; j++) {
    int e = base + j * 1024 + tid;
    v[j] = e < E;
    if (v[j]) {
      d[j] = dst[e];
      s[j] = src[e];
      float2 t = ea[e];
      a[j] = h2u(__builtin_amdgcn_cvt_pkrtz(t.x, t.y));
      atomicAdd(&h[d[j] >> 8], 1);
    }
  }
  __syncthreads();
  for (int i = tid; i < NBUCK; i += 1024) {
    int c = h[i];
    h[i] = c ? atomicAdd(&bucketCur[i], c) : 0;
  }
  __syncthreads();
#pragma unroll
  for (int j = 0; j < 8; j++) {
    if (v[j]) {
      int pos = atomicAdd(&h[d[j] >> 8], 1);
      ERec t; t.s = s[j]; t.d = d[j]; t.ea = a[j];
      brec[pos] = t;
    }
  }
}

// per-bucket degree via LDS histogram (256 nodes/bucket, 512 threads)
__global__ __launch_bounds__(512) void deg_kernel(const ERec* __restrict__ brec,
                                                  const int* __restrict__ bucketOff,
                                                  int* __restrict__ deg, int N) {
  __shared__ int cnt[256];
  int b = blockIdx.x, tid = threadIdx.x;
  if (tid < 256) cnt[tid] = 0;
  __syncthreads();
  int e0 = bucketOff[b], e1 = bucketOff[b + 1];
  for (int i = e0 + tid; i < e1; i += 512) atomicAdd(&cnt[brec[i].d & 255], 1);
  __syncthreads();
  int node = b * 256 + tid;
  if (tid < 256 && node < N) deg[node] = cnt[tid];
}

// ---- 3-phase exclusive scan over PADDED deg ((deg+3)&~3) -> cursor ----
__global__ void scanA_kernel(const int* __restrict__ deg, int* __restrict__ part, int n) {
  __shared__ int ws[16];
  int tid = threadIdx.x;
  int i = blockIdx.x * 1024 + tid;
  int v = 0;
  if (i < n) v = (deg[i] + 3) & ~3;
#pragma unroll
  for (int off = 32; off >= 1; off >>= 1) v += __shfl_down(v, off, 64);
  if ((tid & 63) == 0) ws[tid >> 6] = v;
  __syncthreads();
  if (tid == 0) {
    int s = 0;
#pragma unroll
    for (int k = 0; k < 16; k++) s += ws[k];
    part[blockIdx.x] = s;
  }
}

__global__ void scanB_kernel(int* __restrict__ part, int P, int* __restrict__ etot) {
  int lane = threadIdx.x;
  int carry = 0;
  for (int base = 0; base < P; base += 64) {
    int i = base + lane;
    int v = (i < P) ? part[i] : 0;
    int x = v;
#pragma unroll
    for (int off = 1; off < 64; off <<= 1) {
      int t = __shfl_up(x, off, 64);
      if (lane >= off) x += t;
    }
    if (i < P) part[i] = carry + x - v;
    carry += __shfl(x, 63, 64);
  }
  if (lane == 0) *etot = carry;  // total padded edge count
}

__global__ void scanC_kernel(const int* __restrict__ deg, const int* __restrict__ part,
                             int* __restrict__ cursor, int n) {
  __shared__ int wsum[16];
  __shared__ int woff[16];
  int tid = threadIdx.x, lane = tid & 63, wid = tid >> 6;
  int i = blockIdx.x * 1024 + tid;
  int v = 0;
  if (i < n) v = (deg[i] + 3) & ~3;
  int x = v;
#pragma unroll
  for (int off = 1; off < 64; off <<= 1) {
    int t = __shfl_up(x, off, 64);
    if (lane >= off) x += t;
  }
  if (lane == 63) wsum[wid] = x;
  __syncthreads();
  if (wid == 0) {
    int s = (lane < 16) ? wsum[lane] : 0;
#pragma unroll
    for (int off = 1; off < 16; off <<= 1) {
      int t = __shfl_up(s, off, 64);
      if (lane >= off) s += t;
    }
    if (lane < 16) woff[lane] = s - wsum[lane];
  }
  __syncthreads();
  if (i < n) cursor[i] = part[blockIdx.x] + woff[wid] + x - v;
}

// per-bucket final scatter into padded per-node regions; pad slots filled with
// a DUPLICATE real edge (max idempotent) so all dst-runs are 4-aligned.
// 256-node buckets, 512 threads.
__global__ __launch_bounds__(512) void scat_kernel(
    const ERec* __restrict__ brec, const int* __restrict__ bucketOff,
    const int* __restrict__ cursor, ERec* __restrict__ erec, int N) {
  __shared__ int lcur[256];
  int b = blockIdx.x, tid = threadIdx.x;
  int node = b * 256 + tid;
  if (tid < 256) lcur[tid] = (node < N) ? cursor[node] : 0;
  __syncthreads();
  int e0 = bucketOff[b], e1 = bucketOff[b + 1];
  for (int i = e0 + tid; i < e1; i += 512) {
    ERec t = brec[i];
    int pos = atomicAdd(&lcur[t.d & 255], 1);
    erec[pos] = t;
  }
  __syncthreads();
  if (tid < 256 && node < N) {
    int cur = cursor[node];
    int endR = lcur[tid];                       // cur + real deg
    int endP = cur + ((endR - cur + 3) & ~3);   // cur + padded deg
    if (endR > cur) {
      ERec rep = erec[cur];
      for (int k = endR; k < endP; k++) erec[k] = rep;
    }
  }
}

// pack x to fp16 pairs + zero agg32 rows (N+1 rows x 32 dwords)
__global__ void xpack_kernel(const float* __restrict__ x, uint2* __restrict__ xpk,
                             unsigned int* __restrict__ agg32, int n) {
  int i = blockIdx.x * blockDim.x + threadIdx.x;
  if (i < n) {
    h2 a = __builtin_amdgcn_cvt_pkrtz(x[3 * i], x[3 * i + 1]);
    h2 b = __builtin_amdgcn_cvt_pkrtz(x[3 * i + 2], 0.f);
    xpk[i] = make_uint2(h2u(a), h2u(b));
    uint4 z = make_uint4(0u, 0u, 0u, 0u);
    uint4* ap = (uint4*)(agg32 + (size_t)i * 32);
#pragma unroll
    for (int k = 0; k < 8; k++) ap[k] = z;
    if (i == 0) {
      uint4* as = (uint4*)(agg32 + (size_t)n * 32);
#pragma unroll
      for (int k = 0; k < 8; k++) as[k] = z;
    }
  }
}

// edge kernel (R12 config — the proven-best one): 1 edge/lane, 64-edge window.
// Layer1 5->16 fp16 dot2 (lane=edge), m1 via wave-private LDS tile (stride 12
// dwords, conflict-free), layer2 16->32 via TWO mfma_f32_32x32x16_f16.
// D layout: col=lane&31 (feature), row=(reg&3)+8*(reg>>2)+4*(lane>>5).
// VGPR 44 / LDS 12KB keeps 8 waves/SIMD — R5 showed 2 edges/lane pushes VGPR
// past the 64-reg cliff (72 VGPR -> 4 waves/SIMD) and REGRESSES 35->54us:
// this kernel lives on TLP, not ILP.
__global__ __launch_bounds__(256) void edge_kernel(
    const uint2* __restrict__ xpk, const ERec* __restrict__ erec,
    unsigned int* __restrict__ agg32,
    const float* __restrict__ wg, const int* __restrict__ pEtot, int N) {
  __shared__ __align__(16) unsigned int lds[4][64][12];  // 48B stride/edge row
  const unsigned int* wp = (const unsigned int*)(wg + PKOFS);
  const float* bf = (const float*)wp;
  const int Etot = *pEtot;
  if (blockIdx.x * 256 >= Etot) return;   // whole-block tail skip
  const int tid = threadIdx.x;
  const int lane = tid & 63;
  const int wslot = tid >> 6;
  const int e = blockIdx.x * 256 + tid;

  bool vld = e < Etot;
  ERec r;
  r.s = 0; r.d = N; r.ea = 0u;   // sentinel run (skipped at atomic)
  if (vld) r = erec[e];
  int d = r.d;
  uint2 xs = xpk[r.s];

  // ---- layer1: 5->16 fp16 dot2, packed relu output m1[8] (16 fp16) ----
  h2 p01 = u2h(xs.x), p2v = u2h(xs.y), pea = u2h(r.ea);
  unsigned int m1[8];
#pragma unroll
  for (int p = 0; p < 8; p++) {
    const int oA = 2 * p, oB = 2 * p + 1;
    float sA = DOT2(p01, u2h(wp[oA]),
                DOT2(p2v, u2h(wp[16 + oA]),
                DOT2(pea, u2h(wp[32 + oA]), bf[304 + oA])));
    float sB = DOT2(p01, u2h(wp[oB]),
                DOT2(p2v, u2h(wp[16 + oB]),
                DOT2(pea, u2h(wp[32 + oB]), bf[304 + oB])));
    m1[p] = h2u(__builtin_amdgcn_cvt_pkrtz(fmaxf(sA, 0.f), fmaxf(sB, 0.f)));
  }

  // ---- stage m1 into wave-private LDS slice (stride 12 dwords) ----
  uint4* rowp = (uint4*)&lds[wslot][lane][0];
  rowp[0] = make_uint4(m1[0], m1[1], m1[2], m1[3]);
  rowp[1] = make_uint4(m1[4], m1[5], m1[6], m1[7]);
  // wave-private tile: only need LDS write-drain, not a block barrier
  asm volatile("s_waitcnt lgkmcnt(0)" ::: "memory");
  __builtin_amdgcn_sched_barrier(0);

  const int col = lane & 31;   // output feature (D col)
  const int h = lane >> 5;     // k-half / row-half selector
  f16x8 bfrag = __builtin_bit_cast(f16x8, *(const uint4*)&wp[48 + col * 8 + 4 * h]);
  float bias = bf[320 + col];
  f32x16 cini;
#pragma unroll
  for (int i = 0; i < 16; i++) cini[i] = bias;

  f16x8 a0 = __builtin_bit_cast(f16x8, *(const uint4*)&lds[wslot][col][4 * h]);
  f16x8 a1 = __builtin_bit_cast(f16x8, *(const uint4*)&lds[wslot][32 + col][4 * h]);
  f32x16 acc0 = __builtin_amdgcn_mfma_f32_32x32x16_f16(a0, bfrag, cini, 0, 0, 0);
  f32x16 acc1 = __builtin_amdgcn_mfma_f32_32x32x16_f16(a1, bfrag, cini, 0, 0, 0);

  // ---- per-4-edge-block max (relu folded). lane holds blocks 8g+2q+h ----
  float bm[2][4];
#pragma unroll
  for (int q = 0; q < 4; q++) {
    bm[0][q] = fmaxf(fmaxf(acc0[4 * q], acc0[4 * q + 1]),
                     fmaxf(acc0[4 * q + 2], fmaxf(acc0[4 * q + 3], 0.f)));
    bm[1][q] = fmaxf(fmaxf(acc1[4 * q], acc1[4 * q + 1]),
                     fmaxf(acc1[4 * q + 2], fmaxf(acc1[4 * q + 3], 0.f)));
  }

  // ---- run structure: heads only at 4-aligned lanes (padded scatter) ----
  int dp4 = __shfl_up(d, 4, 64);
  bool isHead = ((lane & 3) == 0) && (lane == 0 || d != dp4);
  unsigned long long hm = __ballot(isHead);

  unsigned long long rem = hm;
  while (rem) {
    int a = (int)__builtin_ctzll(rem);
    rem &= rem - 1;
    int b = rem ? (int)__builtin_ctzll(rem) : 64;
    int rd = __shfl(d, a, 64);
    int A = a >> 2, B = b >> 2;   // block range of this run
    float mx = 0.f;
#pragma unroll
    for (int g = 0; g < 2; g++) {
#pragma unroll
      for (int q = 0; q < 4; q++) {
        int blk = 8 * g + 2 * q + h;
        bool in = (blk >= A) && (blk < B);
        mx = fmaxf(mx, in ? bm[g][q] : 0.f);
      }
    }
    mx = fmaxf(mx, __shfl_xor(mx, 32, 64));
    if (lane < 32 && rd < N)
      atomicMax(agg32 + (size_t)rd * 32 + col, __float_as_uint(mx));
  }
}

// node-parallel: read agg row (f32 bits), zero it for next iteration, node MLP.
__global__ __launch_bounds__(256) void node_kernel(
    const float* __restrict__ x, const float* __restrict__ cin,
    float* __restrict__ cout, uint2* __restrict__ xpk,
    float* __restrict__ outFinal, unsigned int* __restrict__ agg32,
    const float* __restrict__ wg, int n) {
  int nid = blockIdx.x * blockDim.x + threadIdx.x;
  if (nid >= n) return;
  uint4* ap = (uint4*)(agg32 + (size_t)nid * 32);
  uint4 q[8];
#pragma unroll
  for (int i = 0; i < 8; i++) q[i] = ap[i];
  uint4 z = make_uint4(0u, 0u, 0u, 0u);
#pragma unroll
  for (int i = 0; i < 8; i++) ap[i] = z;
  float av[32];
#pragma unroll
  for (int i = 0; i < 8; i++) {
    av[4 * i + 0] = __uint_as_float(q[i].x);
    av[4 * i + 1] = __uint_as_float(q[i].y);
    av[4 * i + 2] = __uint_as_float(q[i].z);
    av[4 * i + 3] = __uint_as_float(q[i].w);
  }
  float x0 = x[3 * nid], x1 = x[3 * nid + 1];
  float x2 = cin ? cin[nid] : x[3 * nid + 2];
  float h[16];
#pragma unroll
  for (int o = 0; o < 16; o++) {
    float sa = wg[1200 + o];
    sa = fmaf(wg[640 + o * 35 + 0], x0, sa);
    sa = fmaf(wg[640 + o * 35 + 1], x1, sa);
    sa = fmaf(wg[640 + o * 35 + 2], x2, sa);
#pragma unroll
    for (int k = 0; k < 32; k++) sa = fmaf(wg[640 + o * 35 + 3 + k], av[k], sa);
    h[o] = fmaxf(sa, 0.f);
  }
  float z4 = wg[1232];
#pragma unroll
  for (int k = 0; k < 16; k++) z4 = fmaf(wg[1216 + k], h[k], z4);
  float comb = 1.f / (1.f + expf(-z4));
  cout[nid] = comb;
  ((unsigned int*)xpk)[2 * nid + 1] = h2u(__builtin_amdgcn_cvt_pkrtz(comb, 0.f));
  if (outFinal) {
    outFinal[3 * nid] = x0;
    outFinal[3 * nid + 1] = x1;
    outFinal[3 * nid + 2] = comb;
  }
}

extern "C" void kernel_launch(void* const* d_in, const int* in_sizes, int n_in,
                              void* d_out, int out_size, void* d_ws, size_t ws_size,
                              hipStream_t stream) {
  const float* x = (const float*)d_in[0];
  const float* ea = (const float*)d_in[1];
  const int* eidx = (const int*)d_in[2];
  const int N = in_sizes[0] / 3;
  const int E = in_sizes[1] / 2;
  const int* src = eidx;
  const int* dst = eidx + E;
  const int P = (N + 1023) / 1024;
  const int NBUCK = (N + 255) >> 8;  // dst buckets, 256 nodes each (<=1024 for N<=262144)
  const int EP = E + 3 * N;          // padded-edge upper bound (actual in *etot)

  // ---- workspace carve-up ----
  char* p = (char*)d_ws;
  size_t off = 0;
  auto alloc = [&](size_t bytes) -> char* {
    char* r = p + off;
    off = (off + bytes + 255) & ~(size_t)255;
    return r;
  };
  float* wbuf = (float*)alloc((size_t)(PKOFS + PKTOT) * 4);
  int* deg = (int*)alloc((size_t)N * 4);
  int* part = (int*)alloc((size_t)P * 4);
  int* cursor = (int*)alloc((size_t)N * 4);
  int* bucketOff = (int*)alloc(((size_t)NBUCK + 1) * 4);
  int* bucketCur = (int*)alloc((size_t)NBUCK * 4);
  int* etot = (int*)alloc(4);
  ERec* erec = (ERec*)alloc((size_t)EP * sizeof(ERec));  // 12B/edge
  // UNION region: build-phase AoS brec (12B/edge) aliased with run-phase
  // arrays (agg32 (N+1)*128B ~12.9MB, xpk, bufA/B) — all << E*12B
  char* uni = alloc((size_t)E * 12);
  ERec* brec = (ERec*)uni;
  size_t uoff = 0;
  auto ualloc = [&](size_t bytes) -> char* {
    char* r = uni + uoff;
    uoff = (uoff + bytes + 255) & ~(size_t)255;
    return r;
  };
  unsigned int* agg32 = (unsigned int*)ualloc(((size_t)N + 1) * 32 * 4);
  uint2* xpk = (uint2*)ualloc((size_t)N * 8);
  float* bufA = (float*)ualloc((size_t)N * 4);
  float* bufB = (float*)ualloc((size_t)N * 4);
  (void)ws_size;

  PrepArgs pa;
  for (int l = 0; l < 4; l++) {
    pa.wmu[l] = (const float*)d_in[3 + 6 * l + 0];
    pa.wrho[l] = (const float*)d_in[3 + 6 * l + 1];
    pa.bmu[l] = (const float*)d_in[3 + 6 * l + 2];
    pa.brho[l] = (const float*)d_in[3 + 6 * l + 3];
    pa.epsw[l] = (const float*)d_in[3 + 6 * l + 4];
    pa.epsb[l] = (const float*)d_in[3 + 6 * l + 5];
  }
  pa.out = wbuf;
  pa.bucketCur = bucketCur;
  pa.nbuck = NBUCK;

  const int TB = 256;
  auto blocks = [&](int n) { return dim3((n + TB - 1) / TB); };

  prep_all_kernel<<<dim3(1), dim3(1024), 0, stream>>>(pa);
  bhist_kernel<<<dim3((E + 8191) / 8192), dim3(1024), 0, stream>>>(dst, bucketCur, E, NBUCK);
  scanBk_kernel<<<dim3(1), dim3(1024), 0, stream>>>(bucketCur, bucketOff, NBUCK);
  part_kernel<<<dim3((E + 8191) / 8192), dim3(1024), 0, stream>>>(
      src, dst, (const float2*)ea, bucketCur, brec, E, NBUCK);
  deg_kernel<<<dim3(NBUCK), dim3(512), 0, stream>>>(brec, bucketOff, deg, N);
  scanA_kernel<<<dim3(P), dim3(1024), 0, stream>>>(deg, part, N);
  scanB_kernel<<<dim3(1), dim3(64), 0, stream>>>(part, P, etot);
  scanC_kernel<<<dim3(P), dim3(1024), 0, stream>>>(deg, part, cursor, N);
  scat_kernel<<<dim3(NBUCK), dim3(512), 0, stream>>>(brec, bucketOff, cursor, erec, N);
  xpack_kernel<<<blocks(N), dim3(TB), 0, stream>>>(x, xpk, agg32, N);

  float* outp = (float*)d_out;
  const int ebp = (EP + 255) / 256;
  // iter 1
  edge_kernel<<<dim3(ebp), dim3(TB), 0, stream>>>(xpk, erec, agg32, wbuf, etot, N);
  node_kernel<<<blocks(N), dim3(TB), 0, stream>>>(x, nullptr, bufA, xpk, nullptr,
                                                  agg32, wbuf, N);
  // iter 2
  edge_kernel<<<dim3(ebp), dim3(TB), 0, stream>>>(xpk, erec, agg32, wbuf, etot, N);
  node_kernel<<<blocks(N), dim3(TB), 0, stream>>>(x, bufA, bufB, xpk, nullptr,
                                                  agg32, wbuf, N);
  // iter 3
  edge_kernel<<<dim3(ebp), dim3(TB), 0, stream>>>(xpk, erec, agg32, wbuf, etot, N);
  node_kernel<<<blocks(N), dim3(TB), 0, stream>>>(x, bufB, bufA, xpk, outp,
                                                  agg32, wbuf, N);
}

// Round 7
// 352.358 us; speedup vs baseline: 1.2250x; 1.0349x over previous
//
#include <hip/hip_runtime.h>
#include <math.h>

// ---- weight buffer layout ----
// fp32 section (dwords 0..1232):
// W1[16][5]@0 b1@80 | W2[32][16]@96 b2@608 | W3[16][35]@640 b3@1200 | W4[16]@1216 b4@1232
// packed fp16 section (uint view at dword offset 1280):
// w1a[16]@0 | w1b[16]@16 | w1c[16]@32 | w2pk[32][8]@48 | b1f[16]@304 | b2f[32]@320
#define WTOT  1233
#define PKOFS 1280
#define PKTOT 352

typedef __fp16 h2 __attribute__((ext_vector_type(2)));
typedef __fp16 f16x8 __attribute__((ext_vector_type(8)));
typedef float f32x16 __attribute__((ext_vector_type(16)));

// 12-byte edge record (src, dst, packed ea)
struct ERec { int s; int d; unsigned int ea; };

__device__ __forceinline__ h2 u2h(unsigned int u) { return __builtin_bit_cast(h2, u); }
__device__ __forceinline__ unsigned int h2u(h2 h) { return __builtin_bit_cast(unsigned int, h); }
#define DOT2(a, b, c) __builtin_amdgcn_fdot2((a), (b), (c), false)

__device__ __forceinline__ float softplus_f(float x) {
  return fmaxf(x, 0.f) + log1pf(expf(-fabsf(x)));
}

struct PrepArgs {
  const float* wmu[4]; const float* wrho[4]; const float* epsw[4];
  const float* bmu[4]; const float* brho[4]; const float* epsb[4];
  float* out; int* bucketCur; int* etot; int nbuck;
};

// single block 1024: sample all weights, pack fp16 section, zero bucketCur+etot
__global__ void prep_all_kernel(PrepArgs a) {
  const int wsz[4] = {80, 512, 560, 16};
  const int wof[4] = {0, 96, 640, 1216};
  const int bsz[4] = {16, 32, 16, 1};
  const int bof[4] = {80, 608, 1200, 1232};
  float* wg = a.out;
  int tid = threadIdx.x;
  if (tid < a.nbuck) a.bucketCur[tid] = 0;
  if (tid == 1023) *a.etot = 0;
#pragma unroll
  for (int l = 0; l < 4; l++) {
    for (int i = tid; i < wsz[l]; i += 1024)
      wg[wof[l] + i] = a.wmu[l][i] + softplus_f(a.wrho[l][i]) * a.epsw[l][i];
    for (int i = tid; i < bsz[l]; i += 1024)
      wg[bof[l] + i] = a.bmu[l][i] + softplus_f(a.brho[l][i]) * a.epsb[l][i];
  }
  __syncthreads();
  unsigned int* wp = (unsigned int*)(wg + PKOFS);
  int t = tid;
  if (t < 16) {
    wp[t]      = h2u(h2{(__fp16)wg[t * 5 + 0], (__fp16)wg[t * 5 + 1]});
    wp[16 + t] = h2u(h2{(__fp16)wg[t * 5 + 2], (__fp16)0.f});
    wp[32 + t] = h2u(h2{(__fp16)wg[t * 5 + 3], (__fp16)wg[t * 5 + 4]});
    ((float*)wp)[304 + t] = wg[80 + t];
  }
  if (t < 32) {
    ((float*)wp)[320 + t] = wg[608 + t];
    for (int j = 0; j < 8; j++)
      wp[48 + t * 8 + j] =
          h2u(h2{(__fp16)wg[96 + t * 16 + 2 * j], (__fp16)wg[96 + t * 16 + 2 * j + 1]});
  }
}

// per-block LDS histogram of dst buckets (bucket = dst>>8), flush to bucketCur
__global__ __launch_bounds__(1024) void bhist_kernel(const int* __restrict__ dst,
                                                     int* __restrict__ bucketCur,
                                                     int E, int NBUCK) {
  __shared__ int h[1024];
  int tid = threadIdx.x;
  for (int i = tid; i < NBUCK; i += 1024) h[i] = 0;
  __syncthreads();
  int base = blockIdx.x * 8192;
#pragma unroll
  for (int r = 0; r < 8; r++) {
    int e = base + r * 1024 + tid;
    if (e < E) atomicAdd(&h[dst[e] >> 8], 1);
  }
  __syncthreads();
  for (int i = tid; i < NBUCK; i += 1024) {
    int c = h[i];
    if (c) atomicAdd(&bucketCur[i], c);
  }
}

// single-block exclusive scan over NBUCK (<=1024) counts held in bucketCur;
// writes bucketOff[0..NBUCK] and re-seeds bucketCur with the exclusive offsets
__global__ __launch_bounds__(1024) void scanBk_kernel(int* __restrict__ bucketCur,
                                                      int* __restrict__ bucketOff,
                                                      int NBUCK) {
  __shared__ int wsum[16];
  __shared__ int woff[16];
  int tid = threadIdx.x, lane = tid & 63, wid = tid >> 6;
  int v = (tid < NBUCK) ? bucketCur[tid] : 0;
  int x = v;
#pragma unroll
  for (int off = 1; off < 64; off <<= 1) {
    int t = __shfl_up(x, off, 64);
    if (lane >= off) x += t;
  }
  if (lane == 63) wsum[wid] = x;
  __syncthreads();
  if (wid == 0) {
    int s = (lane < 16) ? wsum[lane] : 0;
#pragma unroll
    for (int off = 1; off < 16; off <<= 1) {
      int t = __shfl_up(s, off, 64);
      if (lane >= off) s += t;
    }
    if (lane < 16) woff[lane] = s - wsum[lane];
  }
  __syncthreads();
  int excl = woff[wid] + x - v;
  if (tid < NBUCK) {
    bucketOff[tid] = excl;
    bucketCur[tid] = excl;
    if (tid == NBUCK - 1) bucketOff[NBUCK] = excl + v;
  }
}

// partition edges into bucket regions: per-block LDS hist -> global reserve ->
// LDS-cursor append. AoS ERec (12B/edge), 8192 edges/block (R3 lesson:
// occupancy >> chunk depth). 256-node buckets (dst>>8): ~21-record chunks
// (~252B) cut write-allocate amplification (R4->R5 verified win).
__global__ __launch_bounds__(1024) void part_kernel(
    const int* __restrict__ src, const int* __restrict__ dst,
    const float2* __restrict__ ea, int* __restrict__ bucketCur,
    ERec* __restrict__ brec, int E, int NBUCK) {
  __shared__ int h[1024];
  int tid = threadIdx.x;
  for (int i = tid; i < NBUCK; i += 1024) h[i] = 0;
  __syncthreads();
  int base = blockIdx.x * 8192;
  int d[8], s[8];
  unsigned int a[8];
  bool v[8];
#pragma unroll
  for (int j = 0; j < 8; j++) {
    int e = base + j * 1024 + tid;
    v[j] = e < E;
    if (v[j]) {
      d[j] = dst[e];
      s[j] = src[e];
      float2 t = ea[e];
      a[j] = h2u(__builtin_amdgcn_cvt_pkrtz(t.x, t.y));
      atomicAdd(&h[d[j] >> 8], 1);
    }
  }
  __syncthreads();
  for (int i = tid; i < NBUCK; i += 1024) {
    int c = h[i];
    h[i] = c ? atomicAdd(&bucketCur[i], c) : 0;
  }
  __syncthreads();
#pragma unroll
  for (int j = 0; j < 8; j++) {
    if (v[j]) {
      int pos = atomicAdd(&h[d[j] >> 8], 1);
      ERec t; t.s = s[j]; t.d = d[j]; t.ea = a[j];
      brec[pos] = t;
    }
  }
}

// scat (R14): self-contained per-bucket build — LDS histogram of the bucket's
// 256 nodes (region ~99KB, L2-hot) -> padded 256-entry LDS scan -> ONE
// atomicAdd(etot) reserves a 4-aligned output region (global node order in
// erec is IRRELEVANT: edge kernel only needs runs contiguous+4-aligned, agg32
// is indexed by node id) -> LDS-cursor scatter -> pad-fill with duplicate
// real edge (max idempotent). Replaces deg_kernel + scanA/B/C + cursor/deg.
__global__ __launch_bounds__(1024) void scat_kernel(
    const ERec* __restrict__ brec, const int* __restrict__ bucketOff,
    int* __restrict__ etot, ERec* __restrict__ erec, int N) {
  __shared__ int cnt[256];     // count -> running cursor
  __shared__ int sstart[256];  // start positions
  __shared__ int wsum[4];
  __shared__ int woff[4];
  __shared__ int sbase;
  int b = blockIdx.x, tid = threadIdx.x;
  int lane = tid & 63, wid = tid >> 6;
  if (tid < 256) cnt[tid] = 0;
  __syncthreads();
  int e0 = bucketOff[b], e1 = bucketOff[b + 1];
  for (int i = e0 + tid; i < e1; i += 1024) atomicAdd(&cnt[brec[i].d & 255], 1);
  __syncthreads();
  // padded exclusive scan over the 256 counts (threads 0..255 = 4 waves)
  int v = 0;
  if (tid < 256) v = (cnt[tid] + 3) & ~3;
  int x = v;
#pragma unroll
  for (int off = 1; off < 64; off <<= 1) {
    int t = __shfl_up(x, off, 64);
    if (lane >= off) x += t;
  }
  if (tid < 256 && lane == 63) wsum[wid] = x;
  __syncthreads();
  if (wid == 0 && lane < 4) {
    int s = wsum[lane];
#pragma unroll
    for (int off = 1; off < 4; off <<= 1) {
      int t = __shfl_up(s, off, 64);
      if (lane >= off) s += t;
    }
    woff[lane] = s - wsum[lane];
    if (lane == 3) sbase = atomicAdd(etot, s);  // s = block padded total
  }
  __syncthreads();
  if (tid < 256) {
    int start = sbase + woff[wid] + x - v;
    sstart[tid] = start;
    cnt[tid] = start;
  }
  __syncthreads();
  for (int i = e0 + tid; i < e1; i += 1024) {
    ERec t = brec[i];
    int pos = atomicAdd(&cnt[t.d & 255], 1);
    erec[pos] = t;
  }
  __syncthreads();
  if (tid < 256) {
    int start = sstart[tid];
    int endR = cnt[tid];                          // start + real deg
    int endP = start + ((endR - start + 3) & ~3); // start + padded deg
    if (endR > start) {
      ERec rep = erec[start];
      for (int k = endR; k < endP; k++) erec[k] = rep;
    }
  }
}

// pack x to fp16 pairs + zero agg32 rows (N+1 rows x 32 dwords; kills poison —
// iteration TAGS handle inter-iteration reset, no per-iter zeroing needed)
__global__ void xpack_kernel(const float* __restrict__ x, uint2* __restrict__ xpk,
                             unsigned int* __restrict__ agg32, int n) {
  int i = blockIdx.x * blockDim.x + threadIdx.x;
  if (i < n) {
    h2 a = __builtin_amdgcn_cvt_pkrtz(x[3 * i], x[3 * i + 1]);
    h2 b = __builtin_amdgcn_cvt_pkrtz(x[3 * i + 2], 0.f);
    xpk[i] = make_uint2(h2u(a), h2u(b));
    uint4 z = make_uint4(0u, 0u, 0u, 0u);
    uint4* ap = (uint4*)(agg32 + (size_t)i * 32);
#pragma unroll
    for (int k = 0; k < 8; k++) ap[k] = z;
    if (i == 0) {
      uint4* as = (uint4*)(agg32 + (size_t)n * 32);
#pragma unroll
      for (int k = 0; k < 8; k++) as[k] = z;
    }
  }
}

// edge kernel (R12 config — proven-best): 1 edge/lane, 64-edge window.
// Layer1 5->16 fp16 dot2 (lane=edge), m1 via wave-private LDS tile (stride 12
// dwords, conflict-free), layer2 16->32 via TWO mfma_f32_32x32x16_f16.
// D layout: col=lane&31 (feature), row=(reg&3)+8*(reg>>2)+4*(lane>>5).
// VGPR 44 / LDS 12KB keeps 8 waves/SIMD — R5 showed 2 edges/lane pushes VGPR
// past the 64-reg cliff and REGRESSES 35->54us: this kernel lives on TLP.
// R14: agg writes are ITERATION-TAGGED: (tag<<30)|(f32bits>>1). Post-ReLU
// bits fit 31 bits; losing 1 mantissa LSB (2^-22 rel) << 0.0039 tolerance.
// Later tag always wins unsigned atomicMax => NO per-iteration agg zeroing.
__global__ __launch_bounds__(256) void edge_kernel(
    const uint2* __restrict__ xpk, const ERec* __restrict__ erec,
    unsigned int* __restrict__ agg32,
    const float* __restrict__ wg, const int* __restrict__ pEtot,
    unsigned int tag, int N) {
  __shared__ __align__(16) unsigned int lds[4][64][12];  // 48B stride/edge row
  const unsigned int* wp = (const unsigned int*)(wg + PKOFS);
  const float* bf = (const float*)wp;
  const int Etot = *pEtot;
  if (blockIdx.x * 256 >= Etot) return;   // whole-block tail skip
  const int tid = threadIdx.x;
  const int lane = tid & 63;
  const int wslot = tid >> 6;
  const int e = blockIdx.x * 256 + tid;

  bool vld = e < Etot;
  ERec r;
  r.s = 0; r.d = N; r.ea = 0u;   // sentinel run (skipped at atomic)
  if (vld) r = erec[e];
  int d = r.d;
  uint2 xs = xpk[r.s];

  // ---- layer1: 5->16 fp16 dot2, packed relu output m1[8] (16 fp16) ----
  h2 p01 = u2h(xs.x), p2v = u2h(xs.y), pea = u2h(r.ea);
  unsigned int m1[8];
#pragma unroll
  for (int p = 0; p < 8; p++) {
    const int oA = 2 * p, oB = 2 * p + 1;
    float sA = DOT2(p01, u2h(wp[oA]),
                DOT2(p2v, u2h(wp[16 + oA]),
                DOT2(pea, u2h(wp[32 + oA]), bf[304 + oA])));
    float sB = DOT2(p01, u2h(wp[oB]),
                DOT2(p2v, u2h(wp[16 + oB]),
                DOT2(pea, u2h(wp[32 + oB]), bf[304 + oB])));
    m1[p] = h2u(__builtin_amdgcn_cvt_pkrtz(fmaxf(sA, 0.f), fmaxf(sB, 0.f)));
  }

  // ---- stage m1 into wave-private LDS slice (stride 12 dwords) ----
  uint4* rowp = (uint4*)&lds[wslot][lane][0];
  rowp[0] = make_uint4(m1[0], m1[1], m1[2], m1[3]);
  rowp[1] = make_uint4(m1[4], m1[5], m1[6], m1[7]);
  // wave-private tile: only need LDS write-drain, not a block barrier
  asm volatile("s_waitcnt lgkmcnt(0)" ::: "memory");
  __builtin_amdgcn_sched_barrier(0);

  const int col = lane & 31;   // output feature (D col)
  const int h = lane >> 5;     // k-half / row-half selector
  f16x8 bfrag = __builtin_bit_cast(f16x8, *(const uint4*)&wp[48 + col * 8 + 4 * h]);
  float bias = bf[320 + col];
  f32x16 cini;
#pragma unroll
  for (int i = 0; i < 16; i++) cini[i] = bias;

  f16x8 a0 = __builtin_bit_cast(f16x8, *(const uint4*)&lds[wslot][col][4 * h]);
  f16x8 a1 = __builtin_bit_cast(f16x8, *(const uint4*)&lds[wslot][32 + col][4 * h]);
  f32x16 acc0 = __builtin_amdgcn_mfma_f32_32x32x16_f16(a0, bfrag, cini, 0, 0, 0);
  f32x16 acc1 = __builtin_amdgcn_mfma_f32_32x32x16_f16(a1, bfrag, cini, 0, 0, 0);

  // ---- per-4-edge-block max (relu folded). lane holds blocks 8g+2q+h ----
  float bm[2][4];
#pragma unroll
  for (int q = 0; q < 4; q++) {
    bm[0][q] = fmaxf(fmaxf(acc0[4 * q], acc0[4 * q + 1]),
                     fmaxf(acc0[4 * q + 2], fmaxf(acc0[4 * q + 3], 0.f)));
    bm[1][q] = fmaxf(fmaxf(acc1[4 * q], acc1[4 * q + 1]),
                     fmaxf(acc1[4 * q + 2], fmaxf(acc1[4 * q + 3], 0.f)));
  }

  // ---- run structure: heads only at 4-aligned lanes (padded scatter) ----
  int dp4 = __shfl_up(d, 4, 64);
  bool isHead = ((lane & 3) == 0) && (lane == 0 || d != dp4);
  unsigned long long hm = __ballot(isHead);

  unsigned long long rem = hm;
  while (rem) {
    int a = (int)__builtin_ctzll(rem);
    rem &= rem - 1;
    int b = rem ? (int)__builtin_ctzll(rem) : 64;
    int rd = __shfl(d, a, 64);
    int A = a >> 2, B = b >> 2;   // block range of this run
    float mx = 0.f;
#pragma unroll
    for (int g = 0; g < 2; g++) {
#pragma unroll
      for (int q = 0; q < 4; q++) {
        int blk = 8 * g + 2 * q + h;
        bool in = (blk >= A) && (blk < B);
        mx = fmaxf(mx, in ? bm[g][q] : 0.f);
      }
    }
    mx = fmaxf(mx, __shfl_xor(mx, 32, 64));
    if (lane < 32 && rd < N) {
      unsigned int bits = __float_as_uint(mx);
      atomicMax(agg32 + (size_t)rd * 32 + col, (tag << 30) | (bits >> 1));
    }
  }
}

// node-parallel: read agg row, TAG-decode (no zeroing pass), node MLP.
__global__ __launch_bounds__(256) void node_kernel(
    const float* __restrict__ x, const float* __restrict__ cin,
    float* __restrict__ cout, uint2* __restrict__ xpk,
    float* __restrict__ outFinal, const unsigned int* __restrict__ agg32,
    const float* __restrict__ wg, unsigned int tag, int n) {
  int nid = blockIdx.x * blockDim.x + threadIdx.x;
  if (nid >= n) return;
  const uint4* ap = (const uint4*)(agg32 + (size_t)nid * 32);
  uint4 q[8];
#pragma unroll
  for (int i = 0; i < 8; i++) q[i] = ap[i];
  float av[32];
#pragma unroll
  for (int i = 0; i < 8; i++) {
    unsigned int w[4] = {q[i].x, q[i].y, q[i].z, q[i].w};
#pragma unroll
    for (int j = 0; j < 4; j++) {
      unsigned int u = ((w[j] >> 30) == tag) ? ((w[j] & 0x3FFFFFFFu) << 1) : 0u;
      av[4 * i + j] = __uint_as_float(u);
    }
  }
  float x0 = x[3 * nid], x1 = x[3 * nid + 1];
  float x2 = cin ? cin[nid] : x[3 * nid + 2];
  float h[16];
#pragma unroll
  for (int o = 0; o < 16; o++) {
    float sa = wg[1200 + o];
    sa = fmaf(wg[640 + o * 35 + 0], x0, sa);
    sa = fmaf(wg[640 + o * 35 + 1], x1, sa);
    sa = fmaf(wg[640 + o * 35 + 2], x2, sa);
#pragma unroll
    for (int k = 0; k < 32; k++) sa = fmaf(wg[640 + o * 35 + 3 + k], av[k], sa);
    h[o] = fmaxf(sa, 0.f);
  }
  float z4 = wg[1232];
#pragma unroll
  for (int k = 0; k < 16; k++) z4 = fmaf(wg[1216 + k], h[k], z4);
  float comb = 1.f / (1.f + expf(-z4));
  cout[nid] = comb;
  ((unsigned int*)xpk)[2 * nid + 1] = h2u(__builtin_amdgcn_cvt_pkrtz(comb, 0.f));
  if (outFinal) {
    outFinal[3 * nid] = x0;
    outFinal[3 * nid + 1] = x1;
    outFinal[3 * nid + 2] = comb;
  }
}

extern "C" void kernel_launch(void* const* d_in, const int* in_sizes, int n_in,
                              void* d_out, int out_size, void* d_ws, size_t ws_size,
                              hipStream_t stream) {
  const float* x = (const float*)d_in[0];
  const float* ea = (const float*)d_in[1];
  const int* eidx = (const int*)d_in[2];
  const int N = in_sizes[0] / 3;
  const int E = in_sizes[1] / 2;
  const int* src = eidx;
  const int* dst = eidx + E;
  const int NBUCK = (N + 255) >> 8;  // dst buckets, 256 nodes each
  const int EP = E + 3 * N;          // padded-edge upper bound (actual in *etot)

  // ---- workspace carve-up ----
  char* p = (char*)d_ws;
  size_t off = 0;
  auto alloc = [&](size_t bytes) -> char* {
    char* r = p + off;
    off = (off + bytes + 255) & ~(size_t)255;
    return r;
  };
  float* wbuf = (float*)alloc((size_t)(PKOFS + PKTOT) * 4);
  int* bucketOff = (int*)alloc(((size_t)NBUCK + 1) * 4);
  int* bucketCur = (int*)alloc((size_t)NBUCK * 4);
  int* etot = (int*)alloc(4);
  ERec* erec = (ERec*)alloc((size_t)EP * sizeof(ERec));  // 12B/edge
  // UNION region: build-phase AoS brec (12B/edge) aliased with run-phase
  // arrays (agg32 (N+1)*128B ~12.9MB, xpk, bufA/B) — all << E*12B
  char* uni = alloc((size_t)E * 12);
  ERec* brec = (ERec*)uni;
  size_t uoff = 0;
  auto ualloc = [&](size_t bytes) -> char* {
    char* r = uni + uoff;
    uoff = (uoff + bytes + 255) & ~(size_t)255;
    return r;
  };
  unsigned int* agg32 = (unsigned int*)ualloc(((size_t)N + 1) * 32 * 4);
  uint2* xpk = (uint2*)ualloc((size_t)N * 8);
  float* bufA = (float*)ualloc((size_t)N * 4);
  float* bufB = (float*)ualloc((size_t)N * 4);
  (void)ws_size;

  PrepArgs pa;
  for (int l = 0; l < 4; l++) {
    pa.wmu[l] = (const float*)d_in[3 + 6 * l + 0];
    pa.wrho[l] = (const float*)d_in[3 + 6 * l + 1];
    pa.bmu[l] = (const float*)d_in[3 + 6 * l + 2];
    pa.brho[l] = (const float*)d_in[3 + 6 * l + 3];
    pa.epsw[l] = (const float*)d_in[3 + 6 * l + 4];
    pa.epsb[l] = (const float*)d_in[3 + 6 * l + 5];
  }
  pa.out = wbuf;
  pa.bucketCur = bucketCur;
  pa.etot = etot;
  pa.nbuck = NBUCK;

  const int TB = 256;
  auto blocks = [&](int n) { return dim3((n + TB - 1) / TB); };

  prep_all_kernel<<<dim3(1), dim3(1024), 0, stream>>>(pa);
  bhist_kernel<<<dim3((E + 8191) / 8192), dim3(1024), 0, stream>>>(dst, bucketCur, E, NBUCK);
  scanBk_kernel<<<dim3(1), dim3(1024), 0, stream>>>(bucketCur, bucketOff, NBUCK);
  part_kernel<<<dim3((E + 8191) / 8192), dim3(1024), 0, stream>>>(
      src, dst, (const float2*)ea, bucketCur, brec, E, NBUCK);
  scat_kernel<<<dim3(NBUCK), dim3(1024), 0, stream>>>(brec, bucketOff, etot, erec, N);
  xpack_kernel<<<blocks(N), dim3(TB), 0, stream>>>(x, xpk, agg32, N);

  float* outp = (float*)d_out;
  const int ebp = (EP + 255) / 256;
  // iter 1
  edge_kernel<<<dim3(ebp), dim3(TB), 0, stream>>>(xpk, erec, agg32, wbuf, etot, 1u, N);
  node_kernel<<<blocks(N), dim3(TB), 0, stream>>>(x, nullptr, bufA, xpk, nullptr,
                                                  agg32, wbuf, 1u, N);
  // iter 2
  edge_kernel<<<dim3(ebp), dim3(TB), 0, stream>>>(xpk, erec, agg32, wbuf, etot, 2u, N);
  node_kernel<<<blocks(N), dim3(TB), 0, stream>>>(x, bufA, bufB, xpk, nullptr,
                                                  agg32, wbuf, 2u, N);
  // iter 3
  edge_kernel<<<dim3(ebp), dim3(TB), 0, stream>>>(xpk, erec, agg32, wbuf, etot, 3u, N);
  node_kernel<<<blocks(N), dim3(TB), 0, stream>>>(x, bufB, bufA, xpk, outp,
                                                  agg32, wbuf, 3u, N);
}

// Round 8
// 345.922 us; speedup vs baseline: 1.2477x; 1.0186x over previous
//
#include <hip/hip_runtime.h>
#include <math.h>

// ---- weight buffer layout ----
// fp32 section (dwords 0..1232):
// W1[16][5]@0 b1@80 | W2[32][16]@96 b2@608 | W3[16][35]@640 b3@1200 | W4[16]@1216 b4@1232
// packed fp16 section (uint view at dword offset 1280):
// w1a[16]@0 | w1b[16]@16 | w1c[16]@32 | w2pk[32][8]@48 | b1f[16]@304 | b2f[32]@320
#define WTOT  1233
#define PKOFS 1280
#define PKTOT 352

typedef __fp16 h2 __attribute__((ext_vector_type(2)));
typedef __fp16 f16x8 __attribute__((ext_vector_type(8)));
typedef float f32x16 __attribute__((ext_vector_type(16)));

// 12-byte edge record (src, dst, packed ea) — build phase only
struct ERec { int s; int d; unsigned int ea; };

__device__ __forceinline__ h2 u2h(unsigned int u) { return __builtin_bit_cast(h2, u); }
__device__ __forceinline__ unsigned int h2u(h2 h) { return __builtin_bit_cast(unsigned int, h); }
#define DOT2(a, b, c) __builtin_amdgcn_fdot2((a), (b), (c), false)

__device__ __forceinline__ float softplus_f(float x) {
  return fmaxf(x, 0.f) + log1pf(expf(-fabsf(x)));
}

struct PrepArgs {
  const float* wmu[4]; const float* wrho[4]; const float* epsw[4];
  const float* bmu[4]; const float* brho[4]; const float* epsb[4];
  float* out; int* bucketCur; int* etot; int nbuck;
};

// single block 1024: sample all weights, pack fp16 section, zero bucketCur+etot
__global__ void prep_all_kernel(PrepArgs a) {
  const int wsz[4] = {80, 512, 560, 16};
  const int wof[4] = {0, 96, 640, 1216};
  const int bsz[4] = {16, 32, 16, 1};
  const int bof[4] = {80, 608, 1200, 1232};
  float* wg = a.out;
  int tid = threadIdx.x;
  if (tid < a.nbuck) a.bucketCur[tid] = 0;
  if (tid == 1023) *a.etot = 0;
#pragma unroll
  for (int l = 0; l < 4; l++) {
    for (int i = tid; i < wsz[l]; i += 1024)
      wg[wof[l] + i] = a.wmu[l][i] + softplus_f(a.wrho[l][i]) * a.epsw[l][i];
    for (int i = tid; i < bsz[l]; i += 1024)
      wg[bof[l] + i] = a.bmu[l][i] + softplus_f(a.brho[l][i]) * a.epsb[l][i];
  }
  __syncthreads();
  unsigned int* wp = (unsigned int*)(wg + PKOFS);
  int t = tid;
  if (t < 16) {
    wp[t]      = h2u(h2{(__fp16)wg[t * 5 + 0], (__fp16)wg[t * 5 + 1]});
    wp[16 + t] = h2u(h2{(__fp16)wg[t * 5 + 2], (__fp16)0.f});
    wp[32 + t] = h2u(h2{(__fp16)wg[t * 5 + 3], (__fp16)wg[t * 5 + 4]});
    ((float*)wp)[304 + t] = wg[80 + t];
  }
  if (t < 32) {
    ((float*)wp)[320 + t] = wg[608 + t];
    for (int j = 0; j < 8; j++)
      wp[48 + t * 8 + j] =
          h2u(h2{(__fp16)wg[96 + t * 16 + 2 * j], (__fp16)wg[96 + t * 16 + 2 * j + 1]});
  }
}

// per-block LDS histogram of dst buckets (bucket = dst>>8), flush to bucketCur
__global__ __launch_bounds__(1024) void bhist_kernel(const int* __restrict__ dst,
                                                     int* __restrict__ bucketCur,
                                                     int E, int NBUCK) {
  __shared__ int h[1024];
  int tid = threadIdx.x;
  for (int i = tid; i < NBUCK; i += 1024) h[i] = 0;
  __syncthreads();
  int base = blockIdx.x * 8192;
#pragma unroll
  for (int r = 0; r < 8; r++) {
    int e = base + r * 1024 + tid;
    if (e < E) atomicAdd(&h[dst[e] >> 8], 1);
  }
  __syncthreads();
  for (int i = tid; i < NBUCK; i += 1024) {
    int c = h[i];
    if (c) atomicAdd(&bucketCur[i], c);
  }
}

// single-block exclusive scan over NBUCK (<=1024) counts held in bucketCur;
// writes bucketOff[0..NBUCK] and re-seeds bucketCur with the exclusive offsets
__global__ __launch_bounds__(1024) void scanBk_kernel(int* __restrict__ bucketCur,
                                                      int* __restrict__ bucketOff,
                                                      int NBUCK) {
  __shared__ int wsum[16];
  __shared__ int woff[16];
  int tid = threadIdx.x, lane = tid & 63, wid = tid >> 6;
  int v = (tid < NBUCK) ? bucketCur[tid] : 0;
  int x = v;
#pragma unroll
  for (int off = 1; off < 64; off <<= 1) {
    int t = __shfl_up(x, off, 64);
    if (lane >= off) x += t;
  }
  if (lane == 63) wsum[wid] = x;
  __syncthreads();
  if (wid == 0) {
    int s = (lane < 16) ? wsum[lane] : 0;
#pragma unroll
    for (int off = 1; off < 16; off <<= 1) {
      int t = __shfl_up(s, off, 64);
      if (lane >= off) s += t;
    }
    if (lane < 16) woff[lane] = s - wsum[lane];
  }
  __syncthreads();
  int excl = woff[wid] + x - v;
  if (tid < NBUCK) {
    bucketOff[tid] = excl;
    bucketCur[tid] = excl;
    if (tid == NBUCK - 1) bucketOff[NBUCK] = excl + v;
  }
}

// partition edges into bucket regions: per-block LDS hist -> global reserve ->
// LDS-cursor append. AoS ERec (12B/edge), 8192 edges/block (R3 lesson:
// occupancy >> chunk depth). 256-node buckets (dst>>8): ~21-record chunks
// (~252B) cut write-allocate amplification (R4->R5 verified win).
__global__ __launch_bounds__(1024) void part_kernel(
    const int* __restrict__ src, const int* __restrict__ dst,
    const float2* __restrict__ ea, int* __restrict__ bucketCur,
    ERec* __restrict__ brec, int E, int NBUCK) {
  __shared__ int h[1024];
  int tid = threadIdx.x;
  for (int i = tid; i < NBUCK; i += 1024) h[i] = 0;
  __syncthreads();
  int base = blockIdx.x * 8192;
  int d[8], s[8];
  unsigned int a[8];
  bool v[8];
#pragma unroll
  for (int j = 0; j < 8; j++) {
    int e = base + j * 1024 + tid;
    v[j] = e < E;
    if (v[j]) {
      d[j] = dst[e];
      s[j] = src[e];
      float2 t = ea[e];
      a[j] = h2u(__builtin_amdgcn_cvt_pkrtz(t.x, t.y));
      atomicAdd(&h[d[j] >> 8], 1);
    }
  }
  __syncthreads();
  for (int i = tid; i < NBUCK; i += 1024) {
    int c = h[i];
    h[i] = c ? atomicAdd(&bucketCur[i], c) : 0;
  }
  __syncthreads();
#pragma unroll
  for (int j = 0; j < 8; j++) {
    if (v[j]) {
      int pos = atomicAdd(&h[d[j] >> 8], 1);
      ERec t; t.s = s[j]; t.d = d[j]; t.ea = a[j];
      brec[pos] = t;
    }
  }
}

// scat (R15): self-contained per-bucket build — LDS histogram -> padded LDS
// scan -> ONE atomicAdd(etot) reserves a 4-aligned region -> LDS-cursor
// scatter -> pad-fill. Output is SPLIT: se8[e]={src,ea} (8B) + d4[e>>2]=dst
// (dst constant within each 4-aligned block => 1 dword per 4 edges; cuts the
// edge-pass stream from 12B to 9B/edge, read 3x per launch).
__global__ __launch_bounds__(1024) void scat_kernel(
    const ERec* __restrict__ brec, const int* __restrict__ bucketOff,
    int* __restrict__ etot, uint2* __restrict__ se8, unsigned int* __restrict__ d4,
    int N) {
  __shared__ int cnt[256];     // count -> running cursor
  __shared__ int sstart[256];  // start positions
  __shared__ int wsum[4];
  __shared__ int woff[4];
  __shared__ int sbase;
  int b = blockIdx.x, tid = threadIdx.x;
  int lane = tid & 63, wid = tid >> 6;
  if (tid < 256) cnt[tid] = 0;
  __syncthreads();
  int e0 = bucketOff[b], e1 = bucketOff[b + 1];
  for (int i = e0 + tid; i < e1; i += 1024) atomicAdd(&cnt[brec[i].d & 255], 1);
  __syncthreads();
  // padded exclusive scan over the 256 counts (threads 0..255 = 4 waves)
  int v = 0;
  if (tid < 256) v = (cnt[tid] + 3) & ~3;
  int x = v;
#pragma unroll
  for (int off = 1; off < 64; off <<= 1) {
    int t = __shfl_up(x, off, 64);
    if (lane >= off) x += t;
  }
  if (tid < 256 && lane == 63) wsum[wid] = x;
  __syncthreads();
  if (wid == 0 && lane < 4) {
    int s = wsum[lane];
#pragma unroll
    for (int off = 1; off < 4; off <<= 1) {
      int t = __shfl_up(s, off, 64);
      if (lane >= off) s += t;
    }
    woff[lane] = s - wsum[lane];
    if (lane == 3) sbase = atomicAdd(etot, s);  // s = block padded total
  }
  __syncthreads();
  if (tid < 256) {
    int start = sbase + woff[wid] + x - v;
    sstart[tid] = start;
    cnt[tid] = start;
  }
  __syncthreads();
  for (int i = e0 + tid; i < e1; i += 1024) {
    ERec t = brec[i];
    int pos = atomicAdd(&cnt[t.d & 255], 1);
    se8[pos] = make_uint2((unsigned int)t.s, t.ea);
  }
  __syncthreads();
  if (tid < 256) {
    int node = b * 256 + tid;
    int start = sstart[tid];
    int endR = cnt[tid];                          // start + real deg
    int endP = start + ((endR - start + 3) & ~3); // start + padded deg
    if (endR > start) {
      uint2 rep = se8[start];
      for (int k = endR; k < endP; k++) se8[k] = rep;
      for (int k = start; k < endP; k += 4) d4[k >> 2] = (unsigned int)node;
    }
  }
}

// pack x to fp16 pairs + zero agg32 rows (N+1 rows x 32 dwords; kills poison —
// iteration TAGS handle inter-iteration reset, no per-iter zeroing needed)
__global__ void xpack_kernel(const float* __restrict__ x, uint2* __restrict__ xpk,
                             unsigned int* __restrict__ agg32, int n) {
  int i = blockIdx.x * blockDim.x + threadIdx.x;
  if (i < n) {
    h2 a = __builtin_amdgcn_cvt_pkrtz(x[3 * i], x[3 * i + 1]);
    h2 b = __builtin_amdgcn_cvt_pkrtz(x[3 * i + 2], 0.f);
    xpk[i] = make_uint2(h2u(a), h2u(b));
    uint4 z = make_uint4(0u, 0u, 0u, 0u);
    uint4* ap = (uint4*)(agg32 + (size_t)i * 32);
#pragma unroll
    for (int k = 0; k < 8; k++) ap[k] = z;
    if (i == 0) {
      uint4* as = (uint4*)(agg32 + (size_t)n * 32);
#pragma unroll
      for (int k = 0; k < 8; k++) as[k] = z;
    }
  }
}

// edge kernel (R15): 1 edge/lane, 64-edge window (R12 proven config: VGPR~44,
// 12KB LDS, lives on TLP — R5 showed 2 edges/lane crosses the 64-VGPR cliff).
// Stream: se8 (8B/edge, coalesced) + d4 (1 dword per 4-edge block; wave reads
// 16 consecutive dwords). Layer1 5->16 fp16 dot2; m1 via wave-private LDS
// tile; layer2 16->32 via TWO mfma_f32_32x32x16_f16 wrapped in s_setprio(1)
// (waves are independent — attn-like regime where setprio measured +4-7%).
// agg writes ITERATION-TAGGED: (tag<<30)|(f32bits>>1) => no per-iter zeroing.
__global__ __launch_bounds__(256) void edge_kernel(
    const uint2* __restrict__ xpk, const uint2* __restrict__ se8,
    const unsigned int* __restrict__ d4, unsigned int* __restrict__ agg32,
    const float* __restrict__ wg, const int* __restrict__ pEtot,
    unsigned int tag, int N) {
  __shared__ __align__(16) unsigned int lds[4][64][12];  // 48B stride/edge row
  const unsigned int* wp = (const unsigned int*)(wg + PKOFS);
  const float* bf = (const float*)wp;
  const int Etot = *pEtot;
  if (blockIdx.x * 256 >= Etot) return;   // whole-block tail skip
  const int tid = threadIdx.x;
  const int lane = tid & 63;
  const int wslot = tid >> 6;
  const int e = blockIdx.x * 256 + tid;

  bool vld = e < Etot;
  uint2 se = vld ? se8[e] : make_uint2(0u, 0u);
  int d = vld ? (int)d4[e >> 2] : N;      // sentinel run (skipped at atomic)
  uint2 xs = xpk[se.x];

  // ---- layer1: 5->16 fp16 dot2, packed relu output m1[8] (16 fp16) ----
  h2 p01 = u2h(xs.x), p2v = u2h(xs.y), pea = u2h(se.y);
  unsigned int m1[8];
#pragma unroll
  for (int p = 0; p < 8; p++) {
    const int oA = 2 * p, oB = 2 * p + 1;
    float sA = DOT2(p01, u2h(wp[oA]),
                DOT2(p2v, u2h(wp[16 + oA]),
                DOT2(pea, u2h(wp[32 + oA]), bf[304 + oA])));
    float sB = DOT2(p01, u2h(wp[oB]),
                DOT2(p2v, u2h(wp[16 + oB]),
                DOT2(pea, u2h(wp[32 + oB]), bf[304 + oB])));
    m1[p] = h2u(__builtin_amdgcn_cvt_pkrtz(fmaxf(sA, 0.f), fmaxf(sB, 0.f)));
  }

  // ---- stage m1 into wave-private LDS slice (stride 12 dwords) ----
  uint4* rowp = (uint4*)&lds[wslot][lane][0];
  rowp[0] = make_uint4(m1[0], m1[1], m1[2], m1[3]);
  rowp[1] = make_uint4(m1[4], m1[5], m1[6], m1[7]);
  // wave-private tile: only need LDS write-drain, not a block barrier
  asm volatile("s_waitcnt lgkmcnt(0)" ::: "memory");
  __builtin_amdgcn_sched_barrier(0);

  const int col = lane & 31;   // output feature (D col)
  const int h = lane >> 5;     // k-half / row-half selector
  f16x8 bfrag = __builtin_bit_cast(f16x8, *(const uint4*)&wp[48 + col * 8 + 4 * h]);
  float bias = bf[320 + col];
  f32x16 cini;
#pragma unroll
  for (int i = 0; i < 16; i++) cini[i] = bias;

  __builtin_amdgcn_s_setprio(1);
  f16x8 a0 = __builtin_bit_cast(f16x8, *(const uint4*)&lds[wslot][col][4 * h]);
  f16x8 a1 = __builtin_bit_cast(f16x8, *(const uint4*)&lds[wslot][32 + col][4 * h]);
  f32x16 acc0 = __builtin_amdgcn_mfma_f32_32x32x16_f16(a0, bfrag, cini, 0, 0, 0);
  f32x16 acc1 = __builtin_amdgcn_mfma_f32_32x32x16_f16(a1, bfrag, cini, 0, 0, 0);

  // ---- per-4-edge-block max (relu folded). lane holds blocks 8g+2q+h ----
  float bm[2][4];
#pragma unroll
  for (int q = 0; q < 4; q++) {
    bm[0][q] = fmaxf(fmaxf(acc0[4 * q], acc0[4 * q + 1]),
                     fmaxf(acc0[4 * q + 2], fmaxf(acc0[4 * q + 3], 0.f)));
    bm[1][q] = fmaxf(fmaxf(acc1[4 * q], acc1[4 * q + 1]),
                     fmaxf(acc1[4 * q + 2], fmaxf(acc1[4 * q + 3], 0.f)));
  }
  __builtin_amdgcn_s_setprio(0);

  // ---- run structure: heads only at 4-aligned lanes (padded scatter) ----
  int dp4 = __shfl_up(d, 4, 64);
  bool isHead = ((lane & 3) == 0) && (lane == 0 || d != dp4);
  unsigned long long hm = __ballot(isHead);

  unsigned long long rem = hm;
  while (rem) {
    int a = (int)__builtin_ctzll(rem);
    rem &= rem - 1;
    int b = rem ? (int)__builtin_ctzll(rem) : 64;
    int rd = __shfl(d, a, 64);
    int A = a >> 2, B = b >> 2;   // block range of this run
    float mx = 0.f;
#pragma unroll
    for (int g = 0; g < 2; g++) {
#pragma unroll
      for (int q = 0; q < 4; q++) {
        int blk = 8 * g + 2 * q + h;
        bool in = (blk >= A) && (blk < B);
        mx = fmaxf(mx, in ? bm[g][q] : 0.f);
      }
    }
    mx = fmaxf(mx, __shfl_xor(mx, 32, 64));
    if (lane < 32 && rd < N) {
      unsigned int bits = __float_as_uint(mx);
      atomicMax(agg32 + (size_t)rd * 32 + col, (tag << 30) | (bits >> 1));
    }
  }
}

// node-parallel: read agg row, TAG-decode (no zeroing pass), node MLP.
__global__ __launch_bounds__(256) void node_kernel(
    const float* __restrict__ x, const float* __restrict__ cin,
    float* __restrict__ cout, uint2* __restrict__ xpk,
    float* __restrict__ outFinal, const unsigned int* __restrict__ agg32,
    const float* __restrict__ wg, unsigned int tag, int n) {
  int nid = blockIdx.x * blockDim.x + threadIdx.x;
  if (nid >= n) return;
  const uint4* ap = (const uint4*)(agg32 + (size_t)nid * 32);
  uint4 q[8];
#pragma unroll
  for (int i = 0; i < 8; i++) q[i] = ap[i];
  float av[32];
#pragma unroll
  for (int i = 0; i < 8; i++) {
    unsigned int w[4] = {q[i].x, q[i].y, q[i].z, q[i].w};
#pragma unroll
    for (int j = 0; j < 4; j++) {
      unsigned int u = ((w[j] >> 30) == tag) ? ((w[j] & 0x3FFFFFFFu) << 1) : 0u;
      av[4 * i + j] = __uint_as_float(u);
    }
  }
  float x0 = x[3 * nid], x1 = x[3 * nid + 1];
  float x2 = cin ? cin[nid] : x[3 * nid + 2];
  float h[16];
#pragma unroll
  for (int o = 0; o < 16; o++) {
    float sa = wg[1200 + o];
    sa = fmaf(wg[640 + o * 35 + 0], x0, sa);
    sa = fmaf(wg[640 + o * 35 + 1], x1, sa);
    sa = fmaf(wg[640 + o * 35 + 2], x2, sa);
#pragma unroll
    for (int k = 0; k < 32; k++) sa = fmaf(wg[640 + o * 35 + 3 + k], av[k], sa);
    h[o] = fmaxf(sa, 0.f);
  }
  float z4 = wg[1232];
#pragma unroll
  for (int k = 0; k < 16; k++) z4 = fmaf(wg[1216 + k], h[k], z4);
  float comb = 1.f / (1.f + expf(-z4));
  cout[nid] = comb;
  ((unsigned int*)xpk)[2 * nid + 1] = h2u(__builtin_amdgcn_cvt_pkrtz(comb, 0.f));
  if (outFinal) {
    outFinal[3 * nid] = x0;
    outFinal[3 * nid + 1] = x1;
    outFinal[3 * nid + 2] = comb;
  }
}

extern "C" void kernel_launch(void* const* d_in, const int* in_sizes, int n_in,
                              void* d_out, int out_size, void* d_ws, size_t ws_size,
                              hipStream_t stream) {
  const float* x = (const float*)d_in[0];
  const float* ea = (const float*)d_in[1];
  const int* eidx = (const int*)d_in[2];
  const int N = in_sizes[0] / 3;
  const int E = in_sizes[1] / 2;
  const int* src = eidx;
  const int* dst = eidx + E;
  const int NBUCK = (N + 255) >> 8;  // dst buckets, 256 nodes each
  const int EP = E + 3 * N;          // padded-edge upper bound (actual in *etot)

  // ---- workspace carve-up ----
  char* p = (char*)d_ws;
  size_t off = 0;
  auto alloc = [&](size_t bytes) -> char* {
    char* r = p + off;
    off = (off + bytes + 255) & ~(size_t)255;
    return r;
  };
  float* wbuf = (float*)alloc((size_t)(PKOFS + PKTOT) * 4);
  int* bucketOff = (int*)alloc(((size_t)NBUCK + 1) * 4);
  int* bucketCur = (int*)alloc((size_t)NBUCK * 4);
  int* etot = (int*)alloc(4);
  uint2* se8 = (uint2*)alloc((size_t)EP * 8);            // {src, ea} per edge
  unsigned int* d4 = (unsigned int*)alloc(((size_t)(EP + 3) / 4 + 1) * 4);
  // UNION region: build-phase AoS brec (12B/edge) aliased with run-phase
  // arrays (agg32 (N+1)*128B ~12.9MB, xpk, bufA/B) — all << E*12B
  char* uni = alloc((size_t)E * 12);
  ERec* brec = (ERec*)uni;
  size_t uoff = 0;
  auto ualloc = [&](size_t bytes) -> char* {
    char* r = uni + uoff;
    uoff = (uoff + bytes + 255) & ~(size_t)255;
    return r;
  };
  unsigned int* agg32 = (unsigned int*)ualloc(((size_t)N + 1) * 32 * 4);
  uint2* xpk = (uint2*)ualloc((size_t)N * 8);
  float* bufA = (float*)ualloc((size_t)N * 4);
  float* bufB = (float*)ualloc((size_t)N * 4);
  (void)ws_size;

  PrepArgs pa;
  for (int l = 0; l < 4; l++) {
    pa.wmu[l] = (const float*)d_in[3 + 6 * l + 0];
    pa.wrho[l] = (const float*)d_in[3 + 6 * l + 1];
    pa.bmu[l] = (const float*)d_in[3 + 6 * l + 2];
    pa.brho[l] = (const float*)d_in[3 + 6 * l + 3];
    pa.epsw[l] = (const float*)d_in[3 + 6 * l + 4];
    pa.epsb[l] = (const float*)d_in[3 + 6 * l + 5];
  }
  pa.out = wbuf;
  pa.bucketCur = bucketCur;
  pa.etot = etot;
  pa.nbuck = NBUCK;

  const int TB = 256;
  auto blocks = [&](int n) { return dim3((n + TB - 1) / TB); };

  prep_all_kernel<<<dim3(1), dim3(1024), 0, stream>>>(pa);
  bhist_kernel<<<dim3((E + 8191) / 8192), dim3(1024), 0, stream>>>(dst, bucketCur, E, NBUCK);
  scanBk_kernel<<<dim3(1), dim3(1024), 0, stream>>>(bucketCur, bucketOff, NBUCK);
  part_kernel<<<dim3((E + 8191) / 8192), dim3(1024), 0, stream>>>(
      src, dst, (const float2*)ea, bucketCur, brec, E, NBUCK);
  scat_kernel<<<dim3(NBUCK), dim3(1024), 0, stream>>>(brec, bucketOff, etot, se8, d4, N);
  xpack_kernel<<<blocks(N), dim3(TB), 0, stream>>>(x, xpk, agg32, N);

  float* outp = (float*)d_out;
  const int ebp = (EP + 255) / 256;
  // iter 1
  edge_kernel<<<dim3(ebp), dim3(TB), 0, stream>>>(xpk, se8, d4, agg32, wbuf, etot, 1u, N);
  node_kernel<<<blocks(N), dim3(TB), 0, stream>>>(x, nullptr, bufA, xpk, nullptr,
                                                  agg32, wbuf, 1u, N);
  // iter 2
  edge_kernel<<<dim3(ebp), dim3(TB), 0, stream>>>(xpk, se8, d4, agg32, wbuf, etot, 2u, N);
  node_kernel<<<blocks(N), dim3(TB), 0, stream>>>(x, bufA, bufB, xpk, nullptr,
                                                  agg32, wbuf, 2u, N);
  // iter 3
  edge_kernel<<<dim3(ebp), dim3(TB), 0, stream>>>(xpk, se8, d4, agg32, wbuf, etot, 3u, N);
  node_kernel<<<blocks(N), dim3(TB), 0, stream>>>(x, bufB, bufA, xpk, outp,
                                                  agg32, wbuf, 3u, N);
}

// Round 9
// 339.856 us; speedup vs baseline: 1.2700x; 1.0178x over previous
//
#include <hip/hip_runtime.h>
#include <math.h>

// ---- weight buffer layout ----
// fp32 section (dwords 0..1232):
// W1[16][5]@0 b1@80 | W2[32][16]@96 b2@608 | W3[16][35]@640 b3@1200 | W4[16]@1216 b4@1232
// packed fp16 section (uint view at dword offset 1280):
// w1a[16]@0 | w1b[16]@16 | w1c[16]@32 | w2pk[32][8]@48 | b1f[16]@304 | b2f[32]@320
#define WTOT  1233
#define PKOFS 1280
#define PKTOT 352

typedef __fp16 h2 __attribute__((ext_vector_type(2)));
typedef __fp16 f16x8 __attribute__((ext_vector_type(8)));
typedef float f32x16 __attribute__((ext_vector_type(16)));

__device__ __forceinline__ h2 u2h(unsigned int u) { return __builtin_bit_cast(h2, u); }
__device__ __forceinline__ unsigned int h2u(h2 h) { return __builtin_bit_cast(unsigned int, h); }
#define DOT2(a, b, c) __builtin_amdgcn_fdot2((a), (b), (c), false)

__device__ __forceinline__ float softplus_f(float x) {
  return fmaxf(x, 0.f) + log1pf(expf(-fabsf(x)));
}

struct PrepArgs {
  const float* wmu[4]; const float* wrho[4]; const float* epsw[4];
  const float* bmu[4]; const float* brho[4]; const float* epsb[4];
  float* out; int* bucketCur; int* etot; int nbuck;
};

// single block 1024: sample all weights, pack fp16 section, zero bucketCur+etot
__global__ void prep_all_kernel(PrepArgs a) {
  const int wsz[4] = {80, 512, 560, 16};
  const int wof[4] = {0, 96, 640, 1216};
  const int bsz[4] = {16, 32, 16, 1};
  const int bof[4] = {80, 608, 1200, 1232};
  float* wg = a.out;
  int tid = threadIdx.x;
  if (tid < a.nbuck) a.bucketCur[tid] = 0;
  if (tid == 1023) *a.etot = 0;
#pragma unroll
  for (int l = 0; l < 4; l++) {
    for (int i = tid; i < wsz[l]; i += 1024)
      wg[wof[l] + i] = a.wmu[l][i] + softplus_f(a.wrho[l][i]) * a.epsw[l][i];
    for (int i = tid; i < bsz[l]; i += 1024)
      wg[bof[l] + i] = a.bmu[l][i] + softplus_f(a.brho[l][i]) * a.epsb[l][i];
  }
  __syncthreads();
  unsigned int* wp = (unsigned int*)(wg + PKOFS);
  int t = tid;
  if (t < 16) {
    wp[t]      = h2u(h2{(__fp16)wg[t * 5 + 0], (__fp16)wg[t * 5 + 1]});
    wp[16 + t] = h2u(h2{(__fp16)wg[t * 5 + 2], (__fp16)0.f});
    wp[32 + t] = h2u(h2{(__fp16)wg[t * 5 + 3], (__fp16)wg[t * 5 + 4]});
    ((float*)wp)[304 + t] = wg[80 + t];
  }
  if (t < 32) {
    ((float*)wp)[320 + t] = wg[608 + t];
    for (int j = 0; j < 8; j++)
      wp[48 + t * 8 + j] =
          h2u(h2{(__fp16)wg[96 + t * 16 + 2 * j], (__fp16)wg[96 + t * 16 + 2 * j + 1]});
  }
}

// per-block LDS histogram of dst buckets (bucket = dst>>8), flush to bucketCur.
// int4-vectorized dst reads (latency-bound kernel: 1/4 the load instructions).
__global__ __launch_bounds__(1024) void bhist_kernel(const int* __restrict__ dst,
                                                     int* __restrict__ bucketCur,
                                                     int E, int NBUCK) {
  __shared__ int h[1024];
  int tid = threadIdx.x;
  for (int i = tid; i < NBUCK; i += 1024) h[i] = 0;
  __syncthreads();
  int base = blockIdx.x * 8192;
#pragma unroll
  for (int r = 0; r < 2; r++) {
    int e = base + r * 4096 + tid * 4;
    if (e + 3 < E) {
      int4 d4v = *(const int4*)(dst + e);
      atomicAdd(&h[d4v.x >> 8], 1);
      atomicAdd(&h[d4v.y >> 8], 1);
      atomicAdd(&h[d4v.z >> 8], 1);
      atomicAdd(&h[d4v.w >> 8], 1);
    } else {
      for (int k = 0; k < 4; k++)
        if (e + k < E) atomicAdd(&h[dst[e + k] >> 8], 1);
    }
  }
  __syncthreads();
  for (int i = tid; i < NBUCK; i += 1024) {
    int c = h[i];
    if (c) atomicAdd(&bucketCur[i], c);
  }
}

// single-block exclusive scan over NBUCK (<=1024) counts held in bucketCur;
// writes bucketOff[0..NBUCK] and re-seeds bucketCur with the exclusive offsets
__global__ __launch_bounds__(1024) void scanBk_kernel(int* __restrict__ bucketCur,
                                                      int* __restrict__ bucketOff,
                                                      int NBUCK) {
  __shared__ int wsum[16];
  __shared__ int woff[16];
  int tid = threadIdx.x, lane = tid & 63, wid = tid >> 6;
  int v = (tid < NBUCK) ? bucketCur[tid] : 0;
  int x = v;
#pragma unroll
  for (int off = 1; off < 64; off <<= 1) {
    int t = __shfl_up(x, off, 64);
    if (lane >= off) x += t;
  }
  if (lane == 63) wsum[wid] = x;
  __syncthreads();
  if (wid == 0) {
    int s = (lane < 16) ? wsum[lane] : 0;
#pragma unroll
    for (int off = 1; off < 16; off <<= 1) {
      int t = __shfl_up(s, off, 64);
      if (lane >= off) s += t;
    }
    if (lane < 16) woff[lane] = s - wsum[lane];
  }
  __syncthreads();
  int excl = woff[wid] + x - v;
  if (tid < NBUCK) {
    bucketOff[tid] = excl;
    bucketCur[tid] = excl;
    if (tid == NBUCK - 1) bucketOff[NBUCK] = excl + v;
  }
}

// partition edges into bucket regions: per-block LDS hist -> global reserve ->
// LDS-cursor append. PACKED 8B/edge record {ea, src|(dst&255)<<24} — dst's
// high bits are implied by the bucket (dst>>8 == b), src fits 24 bits.
// 8192 edges/block (R3 lesson: occupancy >> chunk depth); 256-node buckets.
__global__ __launch_bounds__(1024) void part_kernel(
    const int* __restrict__ src, const int* __restrict__ dst,
    const float2* __restrict__ ea, int* __restrict__ bucketCur,
    uint2* __restrict__ brec8, int E, int NBUCK) {
  __shared__ int h[1024];
  int tid = threadIdx.x;
  for (int i = tid; i < NBUCK; i += 1024) h[i] = 0;
  __syncthreads();
  int base = blockIdx.x * 8192;
  int d[8], s[8];
  unsigned int a[8];
  bool v[8];
#pragma unroll
  for (int j = 0; j < 8; j++) {
    int e = base + j * 1024 + tid;
    v[j] = e < E;
    if (v[j]) {
      d[j] = dst[e];
      s[j] = src[e];
      float2 t = ea[e];
      a[j] = h2u(__builtin_amdgcn_cvt_pkrtz(t.x, t.y));
      atomicAdd(&h[d[j] >> 8], 1);
    }
  }
  __syncthreads();
  for (int i = tid; i < NBUCK; i += 1024) {
    int c = h[i];
    h[i] = c ? atomicAdd(&bucketCur[i], c) : 0;
  }
  __syncthreads();
#pragma unroll
  for (int j = 0; j < 8; j++) {
    if (v[j]) {
      int pos = atomicAdd(&h[d[j] >> 8], 1);
      brec8[pos] = make_uint2(a[j], (unsigned int)s[j] | ((unsigned int)(d[j] & 255) << 24));
    }
  }
}

// scat (R16): self-contained per-bucket build — LDS histogram -> padded LDS
// scan -> ONE atomicAdd(etot) reserves a 4-aligned region -> LDS-cursor
// scatter -> pad-fill. Reads packed 8B brec8 (node = b*256 + (y>>24));
// writes se8[e]={src,ea} (8B) + d4[e>>2]=dst (1 dword per 4-aligned block).
__global__ __launch_bounds__(1024) void scat_kernel(
    const uint2* __restrict__ brec8, const int* __restrict__ bucketOff,
    int* __restrict__ etot, uint2* __restrict__ se8, unsigned int* __restrict__ d4,
    int N) {
  __shared__ int cnt[256];     // count -> running cursor
  __shared__ int sstart[256];  // start positions
  __shared__ int wsum[4];
  __shared__ int woff[4];
  __shared__ int sbase;
  int b = blockIdx.x, tid = threadIdx.x;
  int lane = tid & 63, wid = tid >> 6;
  if (tid < 256) cnt[tid] = 0;
  __syncthreads();
  int e0 = bucketOff[b], e1 = bucketOff[b + 1];
  for (int i = e0 + tid; i < e1; i += 1024) atomicAdd(&cnt[brec8[i].y >> 24], 1);
  __syncthreads();
  // padded exclusive scan over the 256 counts (threads 0..255 = 4 waves)
  int v = 0;
  if (tid < 256) v = (cnt[tid] + 3) & ~3;
  int x = v;
#pragma unroll
  for (int off = 1; off < 64; off <<= 1) {
    int t = __shfl_up(x, off, 64);
    if (lane >= off) x += t;
  }
  if (tid < 256 && lane == 63) wsum[wid] = x;
  __syncthreads();
  if (wid == 0 && lane < 4) {
    int s = wsum[lane];
#pragma unroll
    for (int off = 1; off < 4; off <<= 1) {
      int t = __shfl_up(s, off, 64);
      if (lane >= off) s += t;
    }
    woff[lane] = s - wsum[lane];
    if (lane == 3) sbase = atomicAdd(etot, s);  // s = block padded total
  }
  __syncthreads();
  if (tid < 256) {
    int start = sbase + woff[wid] + x - v;
    sstart[tid] = start;
    cnt[tid] = start;
  }
  __syncthreads();
  for (int i = e0 + tid; i < e1; i += 1024) {
    uint2 t = brec8[i];
    int pos = atomicAdd(&cnt[t.y >> 24], 1);
    se8[pos] = make_uint2(t.y & 0x00FFFFFFu, t.x);
  }
  __syncthreads();
  if (tid < 256) {
    int node = b * 256 + tid;
    int start = sstart[tid];
    int endR = cnt[tid];                          // start + real deg
    int endP = start + ((endR - start + 3) & ~3); // start + padded deg
    if (endR > start) {
      uint2 rep = se8[start];
      for (int k = endR; k < endP; k++) se8[k] = rep;
      for (int k = start; k < endP; k += 4) d4[k >> 2] = (unsigned int)node;
    }
  }
}

// pack x to fp16 pairs + zero agg32 rows (N+1 rows x 32 dwords; kills poison —
// iteration TAGS handle inter-iteration reset, no per-iter zeroing needed)
__global__ void xpack_kernel(const float* __restrict__ x, uint2* __restrict__ xpk,
                             unsigned int* __restrict__ agg32, int n) {
  int i = blockIdx.x * blockDim.x + threadIdx.x;
  if (i < n) {
    h2 a = __builtin_amdgcn_cvt_pkrtz(x[3 * i], x[3 * i + 1]);
    h2 b = __builtin_amdgcn_cvt_pkrtz(x[3 * i + 2], 0.f);
    xpk[i] = make_uint2(h2u(a), h2u(b));
    uint4 z = make_uint4(0u, 0u, 0u, 0u);
    uint4* ap = (uint4*)(agg32 + (size_t)i * 32);
#pragma unroll
    for (int k = 0; k < 8; k++) ap[k] = z;
    if (i == 0) {
      uint4* as = (uint4*)(agg32 + (size_t)n * 32);
#pragma unroll
      for (int k = 0; k < 8; k++) as[k] = z;
    }
  }
}

// edge kernel (R15 config): 1 edge/lane, 64-edge window (VGPR~44, 12KB LDS,
// lives on TLP — R5 showed 2 edges/lane crosses the 64-VGPR cliff).
// Stream: se8 (8B/edge) + d4 (1 dword per 4-edge block). Layer1 5->16 fp16
// dot2; m1 via wave-private LDS tile; layer2 16->32 via TWO
// mfma_f32_32x32x16_f16 in s_setprio(1) (independent waves — attn-like regime).
// agg writes ITERATION-TAGGED: (tag<<30)|(f32bits>>1) => no per-iter zeroing.
__global__ __launch_bounds__(256) void edge_kernel(
    const uint2* __restrict__ xpk, const uint2* __restrict__ se8,
    const unsigned int* __restrict__ d4, unsigned int* __restrict__ agg32,
    const float* __restrict__ wg, const int* __restrict__ pEtot,
    unsigned int tag, int N) {
  __shared__ __align__(16) unsigned int lds[4][64][12];  // 48B stride/edge row
  const unsigned int* wp = (const unsigned int*)(wg + PKOFS);
  const float* bf = (const float*)wp;
  const int Etot = *pEtot;
  if (blockIdx.x * 256 >= Etot) return;   // whole-block tail skip
  const int tid = threadIdx.x;
  const int lane = tid & 63;
  const int wslot = tid >> 6;
  const int e = blockIdx.x * 256 + tid;

  bool vld = e < Etot;
  uint2 se = vld ? se8[e] : make_uint2(0u, 0u);
  int d = vld ? (int)d4[e >> 2] : N;      // sentinel run (skipped at atomic)
  uint2 xs = xpk[se.x];

  // ---- layer1: 5->16 fp16 dot2, packed relu output m1[8] (16 fp16) ----
  h2 p01 = u2h(xs.x), p2v = u2h(xs.y), pea = u2h(se.y);
  unsigned int m1[8];
#pragma unroll
  for (int p = 0; p < 8; p++) {
    const int oA = 2 * p, oB = 2 * p + 1;
    float sA = DOT2(p01, u2h(wp[oA]),
                DOT2(p2v, u2h(wp[16 + oA]),
                DOT2(pea, u2h(wp[32 + oA]), bf[304 + oA])));
    float sB = DOT2(p01, u2h(wp[oB]),
                DOT2(p2v, u2h(wp[16 + oB]),
                DOT2(pea, u2h(wp[32 + oB]), bf[304 + oB])));
    m1[p] = h2u(__builtin_amdgcn_cvt_pkrtz(fmaxf(sA, 0.f), fmaxf(sB, 0.f)));
  }

  // ---- stage m1 into wave-private LDS slice (stride 12 dwords) ----
  uint4* rowp = (uint4*)&lds[wslot][lane][0];
  rowp[0] = make_uint4(m1[0], m1[1], m1[2], m1[3]);
  rowp[1] = make_uint4(m1[4], m1[5], m1[6], m1[7]);
  // wave-private tile: only need LDS write-drain, not a block barrier
  asm volatile("s_waitcnt lgkmcnt(0)" ::: "memory");
  __builtin_amdgcn_sched_barrier(0);

  const int col = lane & 31;   // output feature (D col)
  const int h = lane >> 5;     // k-half / row-half selector
  f16x8 bfrag = __builtin_bit_cast(f16x8, *(const uint4*)&wp[48 + col * 8 + 4 * h]);
  float bias = bf[320 + col];
  f32x16 cini;
#pragma unroll
  for (int i = 0; i < 16; i++) cini[i] = bias;

  __builtin_amdgcn_s_setprio(1);
  f16x8 a0 = __builtin_bit_cast(f16x8, *(const uint4*)&lds[wslot][col][4 * h]);
  f16x8 a1 = __builtin_bit_cast(f16x8, *(const uint4*)&lds[wslot][32 + col][4 * h]);
  f32x16 acc0 = __builtin_amdgcn_mfma_f32_32x32x16_f16(a0, bfrag, cini, 0, 0, 0);
  f32x16 acc1 = __builtin_amdgcn_mfma_f32_32x32x16_f16(a1, bfrag, cini, 0, 0, 0);

  // ---- per-4-edge-block max (relu folded). lane holds blocks 8g+2q+h ----
  float bm[2][4];
#pragma unroll
  for (int q = 0; q < 4; q++) {
    bm[0][q] = fmaxf(fmaxf(acc0[4 * q], acc0[4 * q + 1]),
                     fmaxf(acc0[4 * q + 2], fmaxf(acc0[4 * q + 3], 0.f)));
    bm[1][q] = fmaxf(fmaxf(acc1[4 * q], acc1[4 * q + 1]),
                     fmaxf(acc1[4 * q + 2], fmaxf(acc1[4 * q + 3], 0.f)));
  }
  __builtin_amdgcn_s_setprio(0);

  // ---- run structure: heads only at 4-aligned lanes (padded scatter) ----
  int dp4 = __shfl_up(d, 4, 64);
  bool isHead = ((lane & 3) == 0) && (lane == 0 || d != dp4);
  unsigned long long hm = __ballot(isHead);

  unsigned long long rem = hm;
  while (rem) {
    int a = (int)__builtin_ctzll(rem);
    rem &= rem - 1;
    int b = rem ? (int)__builtin_ctzll(rem) : 64;
    int rd = __shfl(d, a, 64);
    int A = a >> 2, B = b >> 2;   // block range of this run
    float mx = 0.f;
#pragma unroll
    for (int g = 0; g < 2; g++) {
#pragma unroll
      for (int q = 0; q < 4; q++) {
        int blk = 8 * g + 2 * q + h;
        bool in = (blk >= A) && (blk < B);
        mx = fmaxf(mx, in ? bm[g][q] : 0.f);
      }
    }
    mx = fmaxf(mx, __shfl_xor(mx, 32, 64));
    if (lane < 32 && rd < N) {
      unsigned int bits = __float_as_uint(mx);
      atomicMax(agg32 + (size_t)rd * 32 + col, (tag << 30) | (bits >> 1));
    }
  }
}

// node-parallel: read agg row, TAG-decode (no zeroing pass), node MLP.
__global__ __launch_bounds__(256) void node_kernel(
    const float* __restrict__ x, const float* __restrict__ cin,
    float* __restrict__ cout, uint2* __restrict__ xpk,
    float* __restrict__ outFinal, const unsigned int* __restrict__ agg32,
    const float* __restrict__ wg, unsigned int tag, int n) {
  int nid = blockIdx.x * blockDim.x + threadIdx.x;
  if (nid >= n) return;
  const uint4* ap = (const uint4*)(agg32 + (size_t)nid * 32);
  uint4 q[8];
#pragma unroll
  for (int i = 0; i < 8; i++) q[i] = ap[i];
  float av[32];
#pragma unroll
  for (int i = 0; i < 8; i++) {
    unsigned int w[4] = {q[i].x, q[i].y, q[i].z, q[i].w};
#pragma unroll
    for (int j = 0; j < 4; j++) {
      unsigned int u = ((w[j] >> 30) == tag) ? ((w[j] & 0x3FFFFFFFu) << 1) : 0u;
      av[4 * i + j] = __uint_as_float(u);
    }
  }
  float x0 = x[3 * nid], x1 = x[3 * nid + 1];
  float x2 = cin ? cin[nid] : x[3 * nid + 2];
  float h[16];
#pragma unroll
  for (int o = 0; o < 16; o++) {
    float sa = wg[1200 + o];
    sa = fmaf(wg[640 + o * 35 + 0], x0, sa);
    sa = fmaf(wg[640 + o * 35 + 1], x1, sa);
    sa = fmaf(wg[640 + o * 35 + 2], x2, sa);
#pragma unroll
    for (int k = 0; k < 32; k++) sa = fmaf(wg[640 + o * 35 + 3 + k], av[k], sa);
    h[o] = fmaxf(sa, 0.f);
  }
  float z4 = wg[1232];
#pragma unroll
  for (int k = 0; k < 16; k++) z4 = fmaf(wg[1216 + k], h[k], z4);
  float comb = 1.f / (1.f + expf(-z4));
  cout[nid] = comb;
  ((unsigned int*)xpk)[2 * nid + 1] = h2u(__builtin_amdgcn_cvt_pkrtz(comb, 0.f));
  if (outFinal) {
    outFinal[3 * nid] = x0;
    outFinal[3 * nid + 1] = x1;
    outFinal[3 * nid + 2] = comb;
  }
}

extern "C" void kernel_launch(void* const* d_in, const int* in_sizes, int n_in,
                              void* d_out, int out_size, void* d_ws, size_t ws_size,
                              hipStream_t stream) {
  const float* x = (const float*)d_in[0];
  const float* ea = (const float*)d_in[1];
  const int* eidx = (const int*)d_in[2];
  const int N = in_sizes[0] / 3;
  const int E = in_sizes[1] / 2;
  const int* src = eidx;
  const int* dst = eidx + E;
  const int NBUCK = (N + 255) >> 8;  // dst buckets, 256 nodes each
  const int EP = E + 3 * N;          // padded-edge upper bound (actual in *etot)

  // ---- workspace carve-up ----
  char* p = (char*)d_ws;
  size_t off = 0;
  auto alloc = [&](size_t bytes) -> char* {
    char* r = p + off;
    off = (off + bytes + 255) & ~(size_t)255;
    return r;
  };
  float* wbuf = (float*)alloc((size_t)(PKOFS + PKTOT) * 4);
  int* bucketOff = (int*)alloc(((size_t)NBUCK + 1) * 4);
  int* bucketCur = (int*)alloc((size_t)NBUCK * 4);
  int* etot = (int*)alloc(4);
  uint2* se8 = (uint2*)alloc((size_t)EP * 8);            // {src, ea} per edge
  unsigned int* d4 = (unsigned int*)alloc(((size_t)(EP + 3) / 4 + 1) * 4);
  // UNION region: build-phase packed brec8 (8B/edge) aliased with run-phase
  // arrays (agg32 (N+1)*128B ~12.9MB, xpk, bufA/B ~14.6MB) — all < E*8B
  char* uni = alloc((size_t)E * 8);
  uint2* brec8 = (uint2*)uni;
  size_t uoff = 0;
  auto ualloc = [&](size_t bytes) -> char* {
    char* r = uni + uoff;
    uoff = (uoff + bytes + 255) & ~(size_t)255;
    return r;
  };
  unsigned int* agg32 = (unsigned int*)ualloc(((size_t)N + 1) * 32 * 4);
  uint2* xpk = (uint2*)ualloc((size_t)N * 8);
  float* bufA = (float*)ualloc((size_t)N * 4);
  float* bufB = (float*)ualloc((size_t)N * 4);
  (void)ws_size;

  PrepArgs pa;
  for (int l = 0; l < 4; l++) {
    pa.wmu[l] = (const float*)d_in[3 + 6 * l + 0];
    pa.wrho[l] = (const float*)d_in[3 + 6 * l + 1];
    pa.bmu[l] = (const float*)d_in[3 + 6 * l + 2];
    pa.brho[l] = (const float*)d_in[3 + 6 * l + 3];
    pa.epsw[l] = (const float*)d_in[3 + 6 * l + 4];
    pa.epsb[l] = (const float*)d_in[3 + 6 * l + 5];
  }
  pa.out = wbuf;
  pa.bucketCur = bucketCur;
  pa.etot = etot;
  pa.nbuck = NBUCK;

  const int TB = 256;
  auto blocks = [&](int n) { return dim3((n + TB - 1) / TB); };

  prep_all_kernel<<<dim3(1), dim3(1024), 0, stream>>>(pa);
  bhist_kernel<<<dim3((E + 8191) / 8192), dim3(1024), 0, stream>>>(dst, bucketCur, E, NBUCK);
  scanBk_kernel<<<dim3(1), dim3(1024), 0, stream>>>(bucketCur, bucketOff, NBUCK);
  part_kernel<<<dim3((E + 8191) / 8192), dim3(1024), 0, stream>>>(
      src, dst, (const float2*)ea, bucketCur, brec8, E, NBUCK);
  scat_kernel<<<dim3(NBUCK), dim3(1024), 0, stream>>>(brec8, bucketOff, etot, se8, d4, N);
  xpack_kernel<<<blocks(N), dim3(TB), 0, stream>>>(x, xpk, agg32, N);

  float* outp = (float*)d_out;
  const int ebp = (EP + 255) / 256;
  // iter 1
  edge_kernel<<<dim3(ebp), dim3(TB), 0, stream>>>(xpk, se8, d4, agg32, wbuf, etot, 1u, N);
  node_kernel<<<blocks(N), dim3(TB), 0, stream>>>(x, nullptr, bufA, xpk, nullptr,
                                                  agg32, wbuf, 1u, N);
  // iter 2
  edge_kernel<<<dim3(ebp), dim3(TB), 0, stream>>>(xpk, se8, d4, agg32, wbuf, etot, 2u, N);
  node_kernel<<<blocks(N), dim3(TB), 0, stream>>>(x, bufA, bufB, xpk, nullptr,
                                                  agg32, wbuf, 2u, N);
  // iter 3
  edge_kernel<<<dim3(ebp), dim3(TB), 0, stream>>>(xpk, se8, d4, agg32, wbuf, etot, 3u, N);
  node_kernel<<<blocks(N), dim3(TB), 0, stream>>>(x, bufB, bufA, xpk, outp,
                                                  agg32, wbuf, 3u, N);
}

// Round 10
// 326.384 us; speedup vs baseline: 1.3224x; 1.0413x over previous
//
#include <hip/hip_runtime.h>
#include <math.h>

// ---- weight buffer layout ----
// fp32 section (dwords 0..1232):
// W1[16][5]@0 b1@80 | W2[32][16]@96 b2@608 | W3[16][35]@640 b3@1200 | W4[16]@1216 b4@1232
// packed fp16 section (uint view at dword offset 1280):
// w1a[16]@0 | w1b[16]@16 | w1c[16]@32 | w2pk[32][8]@48 | b1f[16]@304 | b2f[32]@320
#define WTOT  1233
#define PKOFS 1280
#define PKTOT 352

// scat LDS staging capacity (edges). Bucket padded size ~8190+768, std ~90 ->
// 12288 is ~45 sigma; fallback path covers the (unreachable) overflow case.
#define SCAT_CAP 12288

typedef __fp16 h2 __attribute__((ext_vector_type(2)));
typedef __fp16 f16x8 __attribute__((ext_vector_type(8)));
typedef float f32x16 __attribute__((ext_vector_type(16)));

__device__ __forceinline__ h2 u2h(unsigned int u) { return __builtin_bit_cast(h2, u); }
__device__ __forceinline__ unsigned int h2u(h2 h) { return __builtin_bit_cast(unsigned int, h); }
#define DOT2(a, b, c) __builtin_amdgcn_fdot2((a), (b), (c), false)

__device__ __forceinline__ float softplus_f(float x) {
  return fmaxf(x, 0.f) + log1pf(expf(-fabsf(x)));
}

struct PrepArgs {
  const float* wmu[4]; const float* wrho[4]; const float* epsw[4];
  const float* bmu[4]; const float* brho[4]; const float* epsb[4];
  float* out; int* bucketCur; int* etot; int nbuck;
};

// single block 1024: sample all weights, pack fp16 section, zero bucketCur+etot
__global__ void prep_all_kernel(PrepArgs a) {
  const int wsz[4] = {80, 512, 560, 16};
  const int wof[4] = {0, 96, 640, 1216};
  const int bsz[4] = {16, 32, 16, 1};
  const int bof[4] = {80, 608, 1200, 1232};
  float* wg = a.out;
  int tid = threadIdx.x;
  if (tid < a.nbuck) a.bucketCur[tid] = 0;
  if (tid == 1023) *a.etot = 0;
#pragma unroll
  for (int l = 0; l < 4; l++) {
    for (int i = tid; i < wsz[l]; i += 1024)
      wg[wof[l] + i] = a.wmu[l][i] + softplus_f(a.wrho[l][i]) * a.epsw[l][i];
    for (int i = tid; i < bsz[l]; i += 1024)
      wg[bof[l] + i] = a.bmu[l][i] + softplus_f(a.brho[l][i]) * a.epsb[l][i];
  }
  __syncthreads();
  unsigned int* wp = (unsigned int*)(wg + PKOFS);
  int t = tid;
  if (t < 16) {
    wp[t]      = h2u(h2{(__fp16)wg[t * 5 + 0], (__fp16)wg[t * 5 + 1]});
    wp[16 + t] = h2u(h2{(__fp16)wg[t * 5 + 2], (__fp16)0.f});
    wp[32 + t] = h2u(h2{(__fp16)wg[t * 5 + 3], (__fp16)wg[t * 5 + 4]});
    ((float*)wp)[304 + t] = wg[80 + t];
  }
  if (t < 32) {
    ((float*)wp)[320 + t] = wg[608 + t];
    for (int j = 0; j < 8; j++)
      wp[48 + t * 8 + j] =
          h2u(h2{(__fp16)wg[96 + t * 16 + 2 * j], (__fp16)wg[96 + t * 16 + 2 * j + 1]});
  }
}

// per-block LDS histogram of dst buckets (bucket = dst>>8) + FUSED xpack &
// agg32-zero for this block's 256-node range (independent work, overlaps the
// histogram's memory phases; saves the separate xpack launch).
__global__ __launch_bounds__(1024) void bhist_kernel(
    const int* __restrict__ dst, int* __restrict__ bucketCur,
    const float* __restrict__ x, uint2* __restrict__ xpk,
    unsigned int* __restrict__ agg32, int E, int N, int NBUCK) {
  __shared__ int h[1024];
  int tid = threadIdx.x;
  for (int i = tid; i < NBUCK; i += 1024) h[i] = 0;
  // fused xpack (256 nodes/block)
  int nbase = blockIdx.x * 256;
  if (tid < 256) {
    int i = nbase + tid;
    if (i < N) {
      h2 a = __builtin_amdgcn_cvt_pkrtz(x[3 * i], x[3 * i + 1]);
      h2 b = __builtin_amdgcn_cvt_pkrtz(x[3 * i + 2], 0.f);
      xpk[i] = make_uint2(h2u(a), h2u(b));
    }
  }
  // fused agg32 zero (rows nbase..nbase+255, incl. sentinel row N): 8 uint4/row
  {
    uint4 z = make_uint4(0u, 0u, 0u, 0u);
    uint4* ap = (uint4*)agg32;
    size_t lim = ((size_t)N + 1) * 8;
    size_t i0 = (size_t)nbase * 8 + tid;
    if (i0 < lim) ap[i0] = z;
    size_t i1 = i0 + 1024;
    if (i1 < (size_t)(nbase + 256) * 8 && i1 < lim) ap[i1] = z;
  }
  __syncthreads();
  int base = blockIdx.x * 8192;
#pragma unroll
  for (int r = 0; r < 2; r++) {
    int e = base + r * 4096 + tid * 4;
    if (e + 3 < E) {
      int4 d4v = *(const int4*)(dst + e);
      atomicAdd(&h[d4v.x >> 8], 1);
      atomicAdd(&h[d4v.y >> 8], 1);
      atomicAdd(&h[d4v.z >> 8], 1);
      atomicAdd(&h[d4v.w >> 8], 1);
    } else {
      for (int k = 0; k < 4; k++)
        if (e + k < E) atomicAdd(&h[dst[e + k] >> 8], 1);
    }
  }
  __syncthreads();
  for (int i = tid; i < NBUCK; i += 1024) {
    int c = h[i];
    if (c) atomicAdd(&bucketCur[i], c);
  }
}

// single-block exclusive scan over NBUCK (<=1024) counts held in bucketCur;
// writes bucketOff[0..NBUCK] and re-seeds bucketCur with the exclusive offsets
__global__ __launch_bounds__(1024) void scanBk_kernel(int* __restrict__ bucketCur,
                                                      int* __restrict__ bucketOff,
                                                      int NBUCK) {
  __shared__ int wsum[16];
  __shared__ int woff[16];
  int tid = threadIdx.x, lane = tid & 63, wid = tid >> 6;
  int v = (tid < NBUCK) ? bucketCur[tid] : 0;
  int x = v;
#pragma unroll
  for (int off = 1; off < 64; off <<= 1) {
    int t = __shfl_up(x, off, 64);
    if (lane >= off) x += t;
  }
  if (lane == 63) wsum[wid] = x;
  __syncthreads();
  if (wid == 0) {
    int s = (lane < 16) ? wsum[lane] : 0;
#pragma unroll
    for (int off = 1; off < 16; off <<= 1) {
      int t = __shfl_up(s, off, 64);
      if (lane >= off) s += t;
    }
    if (lane < 16) woff[lane] = s - wsum[lane];
  }
  __syncthreads();
  int excl = woff[wid] + x - v;
  if (tid < NBUCK) {
    bucketOff[tid] = excl;
    bucketCur[tid] = excl;
    if (tid == NBUCK - 1) bucketOff[NBUCK] = excl + v;
  }
}

// partition edges into bucket regions: per-block LDS hist -> global reserve ->
// LDS-cursor append. PACKED 8B/edge record {ea, src|(dst&255)<<24} — dst's
// high bits are implied by the bucket (dst>>8 == b), src fits 24 bits.
// 8192 edges/block (R3 lesson: occupancy >> chunk depth); 256-node buckets.
__global__ __launch_bounds__(1024) void part_kernel(
    const int* __restrict__ src, const int* __restrict__ dst,
    const float2* __restrict__ ea, int* __restrict__ bucketCur,
    uint2* __restrict__ brec8, int E, int NBUCK) {
  __shared__ int h[1024];
  int tid = threadIdx.x;
  for (int i = tid; i < NBUCK; i += 1024) h[i] = 0;
  __syncthreads();
  int base = blockIdx.x * 8192;
  int d[8], s[8];
  unsigned int a[8];
  bool v[8];
#pragma unroll
  for (int j = 0; j < 8; j++) {
    int e = base + j * 1024 + tid;
    v[j] = e < E;
    if (v[j]) {
      d[j] = dst[e];
      s[j] = src[e];
      float2 t = ea[e];
      a[j] = h2u(__builtin_amdgcn_cvt_pkrtz(t.x, t.y));
      atomicAdd(&h[d[j] >> 8], 1);
    }
  }
  __syncthreads();
  for (int i = tid; i < NBUCK; i += 1024) {
    int c = h[i];
    h[i] = c ? atomicAdd(&bucketCur[i], c) : 0;
  }
  __syncthreads();
#pragma unroll
  for (int j = 0; j < 8; j++) {
    if (v[j]) {
      int pos = atomicAdd(&h[d[j] >> 8], 1);
      brec8[pos] = make_uint2(a[j], (unsigned int)s[j] | ((unsigned int)(d[j] & 255) << 24));
    }
  }
}

// scat (R17): LDS-STAGED per-bucket build. hist -> padded scan -> ONE
// atomicAdd(etot) reserves a 4-aligned region -> scatter into a 96KB LDS
// stage (random 8B stores hit LDS, not HBM) -> pad-fill in LDS -> COALESCED
// uint4 copy-out. Kills the write-allocate amplification that made scat 53MB
// WRITE for 31MB payload. Fallback to direct-global path if a bucket exceeds
// SCAT_CAP (statistically unreachable for uniform dst; correctness-preserving).
__global__ __launch_bounds__(1024) void scat_kernel(
    const uint2* __restrict__ brec8, const int* __restrict__ bucketOff,
    int* __restrict__ etot, uint2* __restrict__ se8, unsigned int* __restrict__ d4,
    int N) {
  __shared__ int cnt[256];     // count -> running cursor
  __shared__ int sstart[256];  // start positions (LDS- or global-relative)
  __shared__ int wsum[4];
  __shared__ int woff[4];
  __shared__ int sbase;
  __shared__ int ptot;
  __shared__ __align__(16) uint2 stage[SCAT_CAP];      // 96KB
  __shared__ unsigned int staged4[SCAT_CAP / 4];       // 12KB
  int b = blockIdx.x, tid = threadIdx.x;
  int lane = tid & 63, wid = tid >> 6;
  if (tid < 256) cnt[tid] = 0;
  __syncthreads();
  int e0 = bucketOff[b], e1 = bucketOff[b + 1];
  for (int i = e0 + tid; i < e1; i += 1024) atomicAdd(&cnt[brec8[i].y >> 24], 1);
  __syncthreads();
  // padded exclusive scan over the 256 counts (threads 0..255 = 4 waves)
  int v = 0;
  if (tid < 256) v = (cnt[tid] + 3) & ~3;
  int x = v;
#pragma unroll
  for (int off = 1; off < 64; off <<= 1) {
    int t = __shfl_up(x, off, 64);
    if (lane >= off) x += t;
  }
  if (tid < 256 && lane == 63) wsum[wid] = x;
  __syncthreads();
  if (wid == 0 && lane < 4) {
    int s = wsum[lane];
#pragma unroll
    for (int off = 1; off < 4; off <<= 1) {
      int t = __shfl_up(s, off, 64);
      if (lane >= off) s += t;
    }
    woff[lane] = s - wsum[lane];
    if (lane == 3) { ptot = s; sbase = atomicAdd(etot, s); }  // s = padded total
  }
  __syncthreads();
  int total = ptot;
  if (total <= SCAT_CAP) {
    // ---- LDS-staged path ----
    if (tid < 256) {
      int start = woff[wid] + x - v;   // LDS-relative
      sstart[tid] = start;
      cnt[tid] = start;
    }
    __syncthreads();
    for (int i = e0 + tid; i < e1; i += 1024) {
      uint2 t = brec8[i];
      int pos = atomicAdd(&cnt[t.y >> 24], 1);
      stage[pos] = make_uint2(t.y & 0x00FFFFFFu, t.x);
    }
    __syncthreads();
    if (tid < 256) {
      int start = sstart[tid];
      int endR = cnt[tid];                          // start + real deg
      int endP = start + ((endR - start + 3) & ~3); // start + padded deg
      if (endR > start) {
        uint2 rep = stage[start];
        for (int k = endR; k < endP; k++) stage[k] = rep;
        unsigned int node = (unsigned int)(b * 256 + tid);
        for (int k = start; k < endP; k += 4) staged4[k >> 2] = node;
      }
    }
    __syncthreads();
    int base = sbase;                 // 4-aligned => 32B-aligned uint4 dst
    uint4* dstp = (uint4*)(se8 + base);
    const uint4* srcp = (const uint4*)stage;
    int n4 = total >> 1;              // total % 4 == 0
    for (int i = tid; i < n4; i += 1024) dstp[i] = srcp[i];
    unsigned int* d4p = d4 + (base >> 2);
    int nd = total >> 2;
    for (int i = tid; i < nd; i += 1024) d4p[i] = staged4[i];
  } else {
    // ---- fallback: direct global scatter (old R16 path) ----
    if (tid < 256) {
      int start = sbase + woff[wid] + x - v;
      sstart[tid] = start;
      cnt[tid] = start;
    }
    __syncthreads();
    for (int i = e0 + tid; i < e1; i += 1024) {
      uint2 t = brec8[i];
      int pos = atomicAdd(&cnt[t.y >> 24], 1);
      se8[pos] = make_uint2(t.y & 0x00FFFFFFu, t.x);
    }
    __syncthreads();
    if (tid < 256) {
      int node = b * 256 + tid;
      int start = sstart[tid];
      int endR = cnt[tid];
      int endP = start + ((endR - start + 3) & ~3);
      if (endR > start) {
        uint2 rep = se8[start];
        for (int k = endR; k < endP; k++) se8[k] = rep;
        for (int k = start; k < endP; k += 4) d4[k >> 2] = (unsigned int)node;
      }
    }
  }
}

// edge kernel (R15 config): 1 edge/lane, 64-edge window (VGPR~44, 12KB LDS,
// lives on TLP — R5 showed 2 edges/lane crosses the 64-VGPR cliff).
// Stream: se8 (8B/edge) + d4 (1 dword per 4-edge block). Layer1 5->16 fp16
// dot2; m1 via wave-private LDS tile; layer2 16->32 via TWO
// mfma_f32_32x32x16_f16 in s_setprio(1) (independent waves — attn-like regime).
// agg writes ITERATION-TAGGED: (tag<<30)|(f32bits>>1) => no per-iter zeroing.
__global__ __launch_bounds__(256) void edge_kernel(
    const uint2* __restrict__ xpk, const uint2* __restrict__ se8,
    const unsigned int* __restrict__ d4, unsigned int* __restrict__ agg32,
    const float* __restrict__ wg, const int* __restrict__ pEtot,
    unsigned int tag, int N) {
  __shared__ __align__(16) unsigned int lds[4][64][12];  // 48B stride/edge row
  const unsigned int* wp = (const unsigned int*)(wg + PKOFS);
  const float* bf = (const float*)wp;
  const int Etot = *pEtot;
  if (blockIdx.x * 256 >= Etot) return;   // whole-block tail skip
  const int tid = threadIdx.x;
  const int lane = tid & 63;
  const int wslot = tid >> 6;
  const int e = blockIdx.x * 256 + tid;

  bool vld = e < Etot;
  uint2 se = vld ? se8[e] : make_uint2(0u, 0u);
  int d = vld ? (int)d4[e >> 2] : N;      // sentinel run (skipped at atomic)
  uint2 xs = xpk[se.x];

  // ---- layer1: 5->16 fp16 dot2, packed relu output m1[8] (16 fp16) ----
  h2 p01 = u2h(xs.x), p2v = u2h(xs.y), pea = u2h(se.y);
  unsigned int m1[8];
#pragma unroll
  for (int p = 0; p < 8; p++) {
    const int oA = 2 * p, oB = 2 * p + 1;
    float sA = DOT2(p01, u2h(wp[oA]),
                DOT2(p2v, u2h(wp[16 + oA]),
                DOT2(pea, u2h(wp[32 + oA]), bf[304 + oA])));
    float sB = DOT2(p01, u2h(wp[oB]),
                DOT2(p2v, u2h(wp[16 + oB]),
                DOT2(pea, u2h(wp[32 + oB]), bf[304 + oB])));
    m1[p] = h2u(__builtin_amdgcn_cvt_pkrtz(fmaxf(sA, 0.f), fmaxf(sB, 0.f)));
  }

  // ---- stage m1 into wave-private LDS slice (stride 12 dwords) ----
  uint4* rowp = (uint4*)&lds[wslot][lane][0];
  rowp[0] = make_uint4(m1[0], m1[1], m1[2], m1[3]);
  rowp[1] = make_uint4(m1[4], m1[5], m1[6], m1[7]);
  // wave-private tile: only need LDS write-drain, not a block barrier
  asm volatile("s_waitcnt lgkmcnt(0)" ::: "memory");
  __builtin_amdgcn_sched_barrier(0);

  const int col = lane & 31;   // output feature (D col)
  const int h = lane >> 5;     // k-half / row-half selector
  f16x8 bfrag = __builtin_bit_cast(f16x8, *(const uint4*)&wp[48 + col * 8 + 4 * h]);
  float bias = bf[320 + col];
  f32x16 cini;
#pragma unroll
  for (int i = 0; i < 16; i++) cini[i] = bias;

  __builtin_amdgcn_s_setprio(1);
  f16x8 a0 = __builtin_bit_cast(f16x8, *(const uint4*)&lds[wslot][col][4 * h]);
  f16x8 a1 = __builtin_bit_cast(f16x8, *(const uint4*)&lds[wslot][32 + col][4 * h]);
  f32x16 acc0 = __builtin_amdgcn_mfma_f32_32x32x16_f16(a0, bfrag, cini, 0, 0, 0);
  f32x16 acc1 = __builtin_amdgcn_mfma_f32_32x32x16_f16(a1, bfrag, cini, 0, 0, 0);

  // ---- per-4-edge-block max (relu folded). lane holds blocks 8g+2q+h ----
  float bm[2][4];
#pragma unroll
  for (int q = 0; q < 4; q++) {
    bm[0][q] = fmaxf(fmaxf(acc0[4 * q], acc0[4 * q + 1]),
                     fmaxf(acc0[4 * q + 2], fmaxf(acc0[4 * q + 3], 0.f)));
    bm[1][q] = fmaxf(fmaxf(acc1[4 * q], acc1[4 * q + 1]),
                     fmaxf(acc1[4 * q + 2], fmaxf(acc1[4 * q + 3], 0.f)));
  }
  __builtin_amdgcn_s_setprio(0);

  // ---- run structure: heads only at 4-aligned lanes (padded scatter) ----
  int dp4 = __shfl_up(d, 4, 64);
  bool isHead = ((lane & 3) == 0) && (lane == 0 || d != dp4);
  unsigned long long hm = __ballot(isHead);

  unsigned long long rem = hm;
  while (rem) {
    int a = (int)__builtin_ctzll(rem);
    rem &= rem - 1;
    int b = rem ? (int)__builtin_ctzll(rem) : 64;
    int rd = __shfl(d, a, 64);
    int A = a >> 2, B = b >> 2;   // block range of this run
    float mx = 0.f;
#pragma unroll
    for (int g = 0; g < 2; g++) {
#pragma unroll
      for (int q = 0; q < 4; q++) {
        int blk = 8 * g + 2 * q + h;
        bool in = (blk >= A) && (blk < B);
        mx = fmaxf(mx, in ? bm[g][q] : 0.f);
      }
    }
    mx = fmaxf(mx, __shfl_xor(mx, 32, 64));
    if (lane < 32 && rd < N) {
      unsigned int bits = __float_as_uint(mx);
      atomicMax(agg32 + (size_t)rd * 32 + col, (tag << 30) | (bits >> 1));
    }
  }
}

// node-parallel: read agg row, TAG-decode (no zeroing pass), node MLP.
__global__ __launch_bounds__(256) void node_kernel(
    const float* __restrict__ x, const float* __restrict__ cin,
    float* __restrict__ cout, uint2* __restrict__ xpk,
    float* __restrict__ outFinal, const unsigned int* __restrict__ agg32,
    const float* __restrict__ wg, unsigned int tag, int n) {
  int nid = blockIdx.x * blockDim.x + threadIdx.x;
  if (nid >= n) return;
  const uint4* ap = (const uint4*)(agg32 + (size_t)nid * 32);
  uint4 q[8];
#pragma unroll
  for (int i = 0; i < 8; i++) q[i] = ap[i];
  float av[32];
#pragma unroll
  for (int i = 0; i < 8; i++) {
    unsigned int w[4] = {q[i].x, q[i].y, q[i].z, q[i].w};
#pragma unroll
    for (int j = 0; j < 4; j++) {
      unsigned int u = ((w[j] >> 30) == tag) ? ((w[j] & 0x3FFFFFFFu) << 1) : 0u;
      av[4 * i + j] = __uint_as_float(u);
    }
  }
  float x0 = x[3 * nid], x1 = x[3 * nid + 1];
  float x2 = cin ? cin[nid] : x[3 * nid + 2];
  float h[16];
#pragma unroll
  for (int o = 0; o < 16; o++) {
    float sa = wg[1200 + o];
    sa = fmaf(wg[640 + o * 35 + 0], x0, sa);
    sa = fmaf(wg[640 + o * 35 + 1], x1, sa);
    sa = fmaf(wg[640 + o * 35 + 2], x2, sa);
#pragma unroll
    for (int k = 0; k < 32; k++) sa = fmaf(wg[640 + o * 35 + 3 + k], av[k], sa);
    h[o] = fmaxf(sa, 0.f);
  }
  float z4 = wg[1232];
#pragma unroll
  for (int k = 0; k < 16; k++) z4 = fmaf(wg[1216 + k], h[k], z4);
  float comb = 1.f / (1.f + expf(-z4));
  cout[nid] = comb;
  ((unsigned int*)xpk)[2 * nid + 1] = h2u(__builtin_amdgcn_cvt_pkrtz(comb, 0.f));
  if (outFinal) {
    outFinal[3 * nid] = x0;
    outFinal[3 * nid + 1] = x1;
    outFinal[3 * nid + 2] = comb;
  }
}

extern "C" void kernel_launch(void* const* d_in, const int* in_sizes, int n_in,
                              void* d_out, int out_size, void* d_ws, size_t ws_size,
                              hipStream_t stream) {
  const float* x = (const float*)d_in[0];
  const float* ea = (const float*)d_in[1];
  const int* eidx = (const int*)d_in[2];
  const int N = in_sizes[0] / 3;
  const int E = in_sizes[1] / 2;
  const int* src = eidx;
  const int* dst = eidx + E;
  const int NBUCK = (N + 255) >> 8;  // dst buckets, 256 nodes each
  const int EP = E + 3 * N;          // padded-edge upper bound (actual in *etot)

  // ---- workspace carve-up ----
  char* p = (char*)d_ws;
  size_t off = 0;
  auto alloc = [&](size_t bytes) -> char* {
    char* r = p + off;
    off = (off + bytes + 255) & ~(size_t)255;
    return r;
  };
  float* wbuf = (float*)alloc((size_t)(PKOFS + PKTOT) * 4);
  int* bucketOff = (int*)alloc(((size_t)NBUCK + 1) * 4);
  int* bucketCur = (int*)alloc((size_t)NBUCK * 4);
  int* etot = (int*)alloc(4);
  uint2* se8 = (uint2*)alloc((size_t)EP * 8);            // {src, ea} per edge
  unsigned int* d4 = (unsigned int*)alloc(((size_t)(EP + 3) / 4 + 1) * 4);
  // agg32/xpk now OUTSIDE the union: bhist initializes them while brec8 is
  // still live (the fused-xpack change).
  unsigned int* agg32 = (unsigned int*)alloc(((size_t)N + 1) * 32 * 4);
  uint2* xpk = (uint2*)alloc((size_t)N * 8);
  // UNION region: build-phase brec8 (8B/edge) aliased with iteration-phase
  // bufA/bufB (brec8 dead after scat).
  char* uni = alloc((size_t)E * 8);
  uint2* brec8 = (uint2*)uni;
  float* bufA = (float*)uni;
  float* bufB = (float*)(uni + (((size_t)N * 4 + 255) & ~(size_t)255));
  (void)ws_size;

  PrepArgs pa;
  for (int l = 0; l < 4; l++) {
    pa.wmu[l] = (const float*)d_in[3 + 6 * l + 0];
    pa.wrho[l] = (const float*)d_in[3 + 6 * l + 1];
    pa.bmu[l] = (const float*)d_in[3 + 6 * l + 2];
    pa.brho[l] = (const float*)d_in[3 + 6 * l + 3];
    pa.epsw[l] = (const float*)d_in[3 + 6 * l + 4];
    pa.epsb[l] = (const float*)d_in[3 + 6 * l + 5];
  }
  pa.out = wbuf;
  pa.bucketCur = bucketCur;
  pa.etot = etot;
  pa.nbuck = NBUCK;

  const int TB = 256;
  auto blocks = [&](int n) { return dim3((n + TB - 1) / TB); };

  prep_all_kernel<<<dim3(1), dim3(1024), 0, stream>>>(pa);
  {
    int gb = (E + 8191) / 8192;
    int gn = (N + 255) / 256;
    int g = gb > gn ? gb : gn;
    bhist_kernel<<<dim3(g), dim3(1024), 0, stream>>>(dst, bucketCur, x, xpk, agg32,
                                                     E, N, NBUCK);
  }
  scanBk_kernel<<<dim3(1), dim3(1024), 0, stream>>>(bucketCur, bucketOff, NBUCK);
  part_kernel<<<dim3((E + 8191) / 8192), dim3(1024), 0, stream>>>(
      src, dst, (const float2*)ea, bucketCur, brec8, E, NBUCK);
  scat_kernel<<<dim3(NBUCK), dim3(1024), 0, stream>>>(brec8, bucketOff, etot, se8, d4, N);

  float* outp = (float*)d_out;
  const int ebp = (EP + 255) / 256;
  // iter 1
  edge_kernel<<<dim3(ebp), dim3(TB), 0, stream>>>(xpk, se8, d4, agg32, wbuf, etot, 1u, N);
  node_kernel<<<blocks(N), dim3(TB), 0, stream>>>(x, nullptr, bufA, xpk, nullptr,
                                                  agg32, wbuf, 1u, N);
  // iter 2
  edge_kernel<<<dim3(ebp), dim3(TB), 0, stream>>>(xpk, se8, d4, agg32, wbuf, etot, 2u, N);
  node_kernel<<<blocks(N), dim3(TB), 0, stream>>>(x, bufA, bufB, xpk, nullptr,
                                                  agg32, wbuf, 2u, N);
  // iter 3
  edge_kernel<<<dim3(ebp), dim3(TB), 0, stream>>>(xpk, se8, d4, agg32, wbuf, etot, 3u, N);
  node_kernel<<<blocks(N), dim3(TB), 0, stream>>>(x, bufB, bufA, xpk, outp,
                                                  agg32, wbuf, 3u, N);
}